// Round 1
// baseline (1037.632 us; speedup 1.0000x reference)
//
#include <hip/hip_runtime.h>
#include <hip/hip_bf16.h>
#include <stdint.h>

typedef __attribute__((ext_vector_type(8))) short bf16x8;
typedef __attribute__((ext_vector_type(4))) float f32x4;

__device__ __forceinline__ unsigned short f2bf(float f) {
  union { float f; uint32_t u; } c; c.f = f;
  uint32_t r = (c.u + 0x7FFFu + ((c.u >> 16) & 1u)) >> 16;
  return (unsigned short)r;
}

struct MlpParams {
  int M;
  const unsigned short* ln;    // gather source A (EDGE/NODE: ln; DEC: le)
  const unsigned short* src2;  // EDGE: le; NODE: aggb
  const int* rowIdx;
  const int* colIdx;
  const float* x;              // ENC scalar input
  const float* W0v;            // ENC layer0 weight [128]
  const unsigned short* Wt0;   // [128][K0] bf16
  const float* b0;
  const unsigned short* Wt1;   // [128][128] bf16
  const float* b1;
  unsigned short* outB;
  float* agg;                  // EDGE
  const float* decW1;
  const float* decB1;
  const float* edge_attr;
  float* dout;
};

// MODE: 0=ENC(scalar layer0), 1=EDGE(concat3 + agg atomics), 2=NODE(concat2), 3=DEC
template<int MODE, int K0>
__global__ __launch_bounds__(256) void mlp_kernel(MlpParams p) {
  __shared__ __align__(16) unsigned short h_lds[64 * 128];
  __shared__ int s_row[64], s_col[64];
  __shared__ float s_dec[2][64];

  const int tid = threadIdx.x;
  const int wave = tid >> 6, lane = tid & 63;
  const int wm = wave >> 1, wn = wave & 1;
  const int l15 = lane & 15, l4 = lane >> 4;
  const int row0 = blockIdx.x * 64;
  const int M = p.M;

  if constexpr (MODE == 1 || MODE == 3) {
    if (tid < 64) {
      int e = row0 + tid; if (e > M - 1) e = M - 1;
      s_row[tid] = p.rowIdx[e];
      s_col[tid] = p.colIdx[e];
    }
    __syncthreads();
  }

  if constexpr (MODE == 0) {
    // layer0: h = relu(x * W0 + b0), rank-1, computed directly in C-layout
    #pragma unroll
    for (int mt = 0; mt < 2; ++mt) {
      #pragma unroll
      for (int r = 0; r < 4; ++r) {
        int rowb = wm * 32 + mt * 16 + l4 * 4 + r;
        int gm = row0 + rowb; if (gm > M - 1) gm = M - 1;
        float xv = p.x[gm];
        #pragma unroll
        for (int nt = 0; nt < 4; ++nt) {
          int colb = wn * 64 + nt * 16 + l15;
          float v = fmaxf(xv * p.W0v[colb] + p.b0[colb], 0.0f);
          h_lds[rowb * 128 + (colb ^ ((rowb & 7) << 3))] = f2bf(v);
        }
      }
    }
  } else {
    f32x4 acc[2][4] = {};
    #pragma unroll
    for (int ks = 0; ks < K0 / 32; ++ks) {
      const int k = ks * 32 + l4 * 8;
      bf16x8 a[2];
      #pragma unroll
      for (int mt = 0; mt < 2; ++mt) {
        int m_loc = wm * 32 + mt * 16 + l15;
        int gm = row0 + m_loc; if (gm > M - 1) gm = M - 1;
        const unsigned short* sp;
        if constexpr (MODE == 1) {
          if (k < 128)      sp = p.ln   + (size_t)s_row[m_loc] * 128 + k;
          else if (k < 256) sp = p.ln   + (size_t)s_col[m_loc] * 128 + (k - 128);
          else              sp = p.src2 + (size_t)gm * 128 + (k - 256);
        } else if constexpr (MODE == 2) {
          if (k < 128)      sp = p.ln   + (size_t)gm * 128 + k;
          else              sp = p.src2 + (size_t)gm * 128 + (k - 128);
        } else {
          sp = p.ln + (size_t)gm * 128 + k;
        }
        a[mt] = *(const bf16x8*)sp;
      }
      bf16x8 b[4];
      #pragma unroll
      for (int nt = 0; nt < 4; ++nt) {
        int n = wn * 64 + nt * 16 + l15;
        b[nt] = *(const bf16x8*)(p.Wt0 + (size_t)n * K0 + k);
      }
      #pragma unroll
      for (int mt = 0; mt < 2; ++mt)
        #pragma unroll
        for (int nt = 0; nt < 4; ++nt)
          acc[mt][nt] = __builtin_amdgcn_mfma_f32_16x16x32_bf16(a[mt], b[nt], acc[mt][nt], 0, 0, 0);
    }

    if constexpr (MODE == 3) {
      // decoder: relu(h)·decW1 reduce, diag overwrite
      float part[2][4] = {};
      #pragma unroll
      for (int mt = 0; mt < 2; ++mt) {
        #pragma unroll
        for (int nt = 0; nt < 4; ++nt) {
          int colb = wn * 64 + nt * 16 + l15;
          float w1 = p.decW1[colb];
          float bb = p.b0[colb];
          #pragma unroll
          for (int r = 0; r < 4; ++r)
            part[mt][r] += fmaxf(acc[mt][nt][r] + bb, 0.0f) * w1;
        }
      }
      #pragma unroll
      for (int mt = 0; mt < 2; ++mt) {
        #pragma unroll
        for (int r = 0; r < 4; ++r) {
          float v = part[mt][r];
          #pragma unroll
          for (int off = 1; off < 16; off <<= 1) v += __shfl_xor(v, off, 64);
          if (l15 == 0) s_dec[wn][wm * 32 + mt * 16 + l4 * 4 + r] = v;
        }
      }
      __syncthreads();
      if (tid < 64) {
        int gm = row0 + tid;
        if (gm < M) {
          float v = s_dec[0][tid] + s_dec[1][tid] + p.decB1[0];
          if (s_row[tid] == s_col[tid]) v = 0.5f * sqrtf(p.edge_attr[gm]);
          p.dout[gm] = v;
        }
      }
      return;
    } else {
      // h = relu(acc + b0) -> LDS (XOR-swizzled)
      #pragma unroll
      for (int mt = 0; mt < 2; ++mt) {
        #pragma unroll
        for (int nt = 0; nt < 4; ++nt) {
          int colb = wn * 64 + nt * 16 + l15;
          float bb = p.b0[colb];
          #pragma unroll
          for (int r = 0; r < 4; ++r) {
            int rowb = wm * 32 + mt * 16 + l4 * 4 + r;
            float v = fmaxf(acc[mt][nt][r] + bb, 0.0f);
            h_lds[rowb * 128 + (colb ^ ((rowb & 7) << 3))] = f2bf(v);
          }
        }
      }
    }
  }

  if constexpr (MODE != 3) {
    __syncthreads();
    // layer1: out = h @ W1 + b1
    f32x4 acc1[2][4] = {};
    #pragma unroll
    for (int ks = 0; ks < 4; ++ks) {
      const int k = ks * 32 + l4 * 8;
      bf16x8 a1[2];
      #pragma unroll
      for (int mt = 0; mt < 2; ++mt) {
        int rowb = wm * 32 + mt * 16 + l15;
        a1[mt] = *(const bf16x8*)&h_lds[rowb * 128 + (k ^ ((rowb & 7) << 3))];
      }
      bf16x8 b1v[4];
      #pragma unroll
      for (int nt = 0; nt < 4; ++nt) {
        int n = wn * 64 + nt * 16 + l15;
        b1v[nt] = *(const bf16x8*)(p.Wt1 + (size_t)n * 128 + k);
      }
      #pragma unroll
      for (int mt = 0; mt < 2; ++mt)
        #pragma unroll
        for (int nt = 0; nt < 4; ++nt)
          acc1[mt][nt] = __builtin_amdgcn_mfma_f32_16x16x32_bf16(a1[mt], b1v[nt], acc1[mt][nt], 0, 0, 0);
    }
    #pragma unroll
    for (int mt = 0; mt < 2; ++mt) {
      #pragma unroll
      for (int nt = 0; nt < 4; ++nt) {
        int colb = wn * 64 + nt * 16 + l15;
        float bb = p.b1[colb];
        #pragma unroll
        for (int r = 0; r < 4; ++r) {
          int rowb = wm * 32 + mt * 16 + l4 * 4 + r;
          int gm = row0 + rowb;
          if (gm < M) {
            float v = acc1[mt][nt][r] + bb;
            p.outB[(size_t)gm * 128 + colb] = f2bf(v);
            if constexpr (MODE == 1)
              atomicAdd(&p.agg[(size_t)s_row[rowb] * 128 + colb], v);
          }
        }
      }
    }
  }
}

struct TransDesc { const float* src[16]; unsigned short* dst[16]; int K[16]; };

__global__ void trans_kernel(TransDesc td) {
  int m = blockIdx.y;
  int k = blockIdx.x;
  if (k >= td.K[m]) return;
  int n = threadIdx.x;  // 128
  td.dst[m][(size_t)n * td.K[m] + k] = f2bf(td.src[m][(size_t)k * 128 + n]);
}

__global__ void deg_kernel(const int* __restrict__ row, int E, int* cnt) {
  int i = blockIdx.x * blockDim.x + threadIdx.x;
  if (i < E) atomicAdd(&cnt[row[i]], 1);
}

__global__ void invcnt_kernel(const int* __restrict__ cnt, int N, float* inv) {
  int i = blockIdx.x * blockDim.x + threadIdx.x;
  if (i < N) { int c = cnt[i]; inv[i] = 1.0f / (float)(c > 1 ? c : 1); }
}

__global__ void aggb_kernel(const float* __restrict__ agg, const float* __restrict__ inv,
                            int total, unsigned short* aggb) {
  int i = blockIdx.x * blockDim.x + threadIdx.x;
  if (i < total) aggb[i] = f2bf(agg[i] * inv[i >> 7]);
}

extern "C" void kernel_launch(void* const* d_in, const int* in_sizes, int n_in,
                              void* d_out, int out_size, void* d_ws, size_t ws_size,
                              hipStream_t stream) {
  const float* x         = (const float*)d_in[0];
  const float* edge_attr = (const float*)d_in[1];
  const int*   eidx      = (const int*)  d_in[2];
  const float* encn_W0 = (const float*)d_in[3];
  const float* encn_b0 = (const float*)d_in[4];
  const float* encn_W1 = (const float*)d_in[5];
  const float* encn_b1 = (const float*)d_in[6];
  const float* ence_W0 = (const float*)d_in[7];
  const float* ence_b0 = (const float*)d_in[8];
  const float* ence_W1 = (const float*)d_in[9];
  const float* ence_b1 = (const float*)d_in[10];
  const float* dec_W0  = (const float*)d_in[11];
  const float* dec_b0  = (const float*)d_in[12];
  const float* dec_W1  = (const float*)d_in[13];
  const float* dec_b1  = (const float*)d_in[14];
  const float* eW0 = (const float*)d_in[15];
  const float* eb0 = (const float*)d_in[16];
  const float* eW1 = (const float*)d_in[17];
  const float* eb1 = (const float*)d_in[18];
  const float* nW0 = (const float*)d_in[19];
  const float* nb0 = (const float*)d_in[20];
  const float* nW1 = (const float*)d_in[21];
  const float* nb1 = (const float*)d_in[22];

  const int N = in_sizes[0];
  const int E = in_sizes[1];
  const int* rowI = eidx;
  const int* colI = eidx + E;

  char* w = (char*)d_ws;
  auto take = [&](size_t bytes) -> char* {
    char* p = w; w += (bytes + 255) & ~(size_t)255; return p;
  };
  unsigned short* ln   = (unsigned short*)take((size_t)N * 128 * 2);
  unsigned short* le   = (unsigned short*)take((size_t)E * 128 * 2);
  float*          agg  = (float*)take((size_t)N * 128 * 4);
  unsigned short* aggb = (unsigned short*)take((size_t)N * 128 * 2);
  int*            cnt  = (int*)take((size_t)N * 4);
  float*          inv  = (float*)take((size_t)N * 4);
  unsigned short* wt_encn1 = (unsigned short*)take(128 * 128 * 2);
  unsigned short* wt_ence1 = (unsigned short*)take(128 * 128 * 2);
  unsigned short* wt_dec0  = (unsigned short*)take(128 * 128 * 2);
  unsigned short *wt_e0[3], *wt_e1[3], *wt_n0[3], *wt_n1[3];
  for (int s = 0; s < 3; ++s) wt_e0[s] = (unsigned short*)take(384 * 128 * 2);
  for (int s = 0; s < 3; ++s) wt_e1[s] = (unsigned short*)take(128 * 128 * 2);
  for (int s = 0; s < 3; ++s) wt_n0[s] = (unsigned short*)take(256 * 128 * 2);
  for (int s = 0; s < 3; ++s) wt_n1[s] = (unsigned short*)take(128 * 128 * 2);

  TransDesc td{};
  int mi = 0;
  auto add = [&](const float* s, unsigned short* d, int K) {
    td.src[mi] = s; td.dst[mi] = d; td.K[mi] = K; ++mi;
  };
  add(encn_W1, wt_encn1, 128);
  add(ence_W1, wt_ence1, 128);
  add(dec_W0,  wt_dec0,  128);
  for (int s = 0; s < 3; ++s) add(eW0 + (size_t)s * 384 * 128, wt_e0[s], 384);
  for (int s = 0; s < 3; ++s) add(eW1 + (size_t)s * 128 * 128, wt_e1[s], 128);
  for (int s = 0; s < 3; ++s) add(nW0 + (size_t)s * 256 * 128, wt_n0[s], 256);
  for (int s = 0; s < 3; ++s) add(nW1 + (size_t)s * 128 * 128, wt_n1[s], 128);

  hipMemsetAsync(cnt, 0, (size_t)N * 4, stream);
  trans_kernel<<<dim3(384, mi), 128, 0, stream>>>(td);
  deg_kernel<<<(E + 255) / 256, 256, 0, stream>>>(rowI, E, cnt);
  invcnt_kernel<<<(N + 255) / 256, 256, 0, stream>>>(cnt, N, inv);

  {
    MlpParams q{}; q.M = N; q.x = x; q.W0v = encn_W0; q.b0 = encn_b0;
    q.Wt1 = wt_encn1; q.b1 = encn_b1; q.outB = ln;
    mlp_kernel<0, 128><<<(N + 63) / 64, 256, 0, stream>>>(q);
  }
  {
    MlpParams q{}; q.M = E; q.x = edge_attr; q.W0v = ence_W0; q.b0 = ence_b0;
    q.Wt1 = wt_ence1; q.b1 = ence_b1; q.outB = le;
    mlp_kernel<0, 128><<<(E + 63) / 64, 256, 0, stream>>>(q);
  }

  for (int s = 0; s < 3; ++s) {
    hipMemsetAsync(agg, 0, (size_t)N * 128 * 4, stream);
    {
      MlpParams q{}; q.M = E; q.ln = ln; q.src2 = le; q.rowIdx = rowI; q.colIdx = colI;
      q.Wt0 = wt_e0[s]; q.b0 = eb0 + s * 128; q.Wt1 = wt_e1[s]; q.b1 = eb1 + s * 128;
      q.outB = le; q.agg = agg;
      mlp_kernel<1, 384><<<(E + 63) / 64, 256, 0, stream>>>(q);
    }
    aggb_kernel<<<(N * 128 + 255) / 256, 256, 0, stream>>>(agg, inv, N * 128, aggb);
    {
      MlpParams q{}; q.M = N; q.ln = ln; q.src2 = aggb;
      q.Wt0 = wt_n0[s]; q.b0 = nb0 + s * 128; q.Wt1 = wt_n1[s]; q.b1 = nb1 + s * 128;
      q.outB = ln;
      mlp_kernel<2, 256><<<(N + 63) / 64, 256, 0, stream>>>(q);
    }
  }
  {
    MlpParams q{}; q.M = E; q.ln = le; q.rowIdx = rowI; q.colIdx = colI;
    q.Wt0 = wt_dec0; q.b0 = dec_b0; q.decW1 = dec_W1; q.decB1 = dec_b1;
    q.edge_attr = edge_attr; q.dout = (float*)d_out;
    mlp_kernel<3, 128><<<(E + 63) / 64, 256, 0, stream>>>(q);
  }
}

// Round 2
// 990.449 us; speedup vs baseline: 1.0476x; 1.0476x over previous
//
#include <hip/hip_runtime.h>
#include <hip/hip_bf16.h>
#include <stdint.h>

typedef __attribute__((ext_vector_type(8))) short bf16x8;
typedef __attribute__((ext_vector_type(4))) float f32x4;

__device__ __forceinline__ unsigned short f2bf(float f) {
  union { float f; uint32_t u; } c; c.f = f;
  uint32_t r = (c.u + 0x7FFFu + ((c.u >> 16) & 1u)) >> 16;
  return (unsigned short)r;
}
__device__ __forceinline__ float bf2f(unsigned short u) {
  union { uint32_t u; float f; } c; c.u = (uint32_t)u << 16; return c.f;
}

struct MlpParams {
  int M;
  const unsigned short* ln;    // gather source A (EDGE/NODE: ln; DEC: le)
  const unsigned short* src2;  // EDGE: le; NODE: aggb
  const int* rowIdx;
  const int* colIdx;
  const float* x;              // ENC scalar input
  const float* W0v;            // ENC layer0 weight [128]
  const unsigned short* Wt0;   // [128][K0] bf16
  const float* b0;
  const unsigned short* Wt1;   // [128][128] bf16
  const float* b1;
  unsigned short* outB;
  const float* decW1;
  const float* decB1;
  const float* edge_attr;
  float* dout;
};

// MODE: 0=ENC(scalar layer0), 1=EDGE(concat3), 2=NODE(concat2), 3=DEC
template<int MODE, int K0>
__global__ __launch_bounds__(256) void mlp_kernel(MlpParams p) {
  __shared__ __align__(16) unsigned short h_lds[64 * 128];
  __shared__ int s_row[64], s_col[64];
  __shared__ float s_dec[2][64];

  const int tid = threadIdx.x;
  const int wave = tid >> 6, lane = tid & 63;
  const int wm = wave >> 1, wn = wave & 1;
  const int l15 = lane & 15, l4 = lane >> 4;
  const int row0 = blockIdx.x * 64;
  const int M = p.M;

  if constexpr (MODE == 1 || MODE == 3) {
    if (tid < 64) {
      int e = row0 + tid; if (e > M - 1) e = M - 1;
      s_row[tid] = p.rowIdx[e];
      s_col[tid] = p.colIdx[e];
    }
    __syncthreads();
  }

  if constexpr (MODE == 0) {
    // layer0: h = relu(x * W0 + b0), rank-1, computed directly in C-layout
    #pragma unroll
    for (int mt = 0; mt < 2; ++mt) {
      #pragma unroll
      for (int r = 0; r < 4; ++r) {
        int rowb = wm * 32 + mt * 16 + l4 * 4 + r;
        int gm = row0 + rowb; if (gm > M - 1) gm = M - 1;
        float xv = p.x[gm];
        #pragma unroll
        for (int nt = 0; nt < 4; ++nt) {
          int colb = wn * 64 + nt * 16 + l15;
          float v = fmaxf(xv * p.W0v[colb] + p.b0[colb], 0.0f);
          h_lds[rowb * 128 + (colb ^ ((rowb & 7) << 3))] = f2bf(v);
        }
      }
    }
  } else {
    f32x4 acc[2][4] = {};
    #pragma unroll
    for (int ks = 0; ks < K0 / 32; ++ks) {
      const int k = ks * 32 + l4 * 8;
      bf16x8 a[2];
      #pragma unroll
      for (int mt = 0; mt < 2; ++mt) {
        int m_loc = wm * 32 + mt * 16 + l15;
        int gm = row0 + m_loc; if (gm > M - 1) gm = M - 1;
        const unsigned short* sp;
        if constexpr (MODE == 1) {
          if (k < 128)      sp = p.ln   + (size_t)s_row[m_loc] * 128 + k;
          else if (k < 256) sp = p.ln   + (size_t)s_col[m_loc] * 128 + (k - 128);
          else              sp = p.src2 + (size_t)gm * 128 + (k - 256);
        } else if constexpr (MODE == 2) {
          if (k < 128)      sp = p.ln   + (size_t)gm * 128 + k;
          else              sp = p.src2 + (size_t)gm * 128 + (k - 128);
        } else {
          sp = p.ln + (size_t)gm * 128 + k;
        }
        a[mt] = *(const bf16x8*)sp;
      }
      bf16x8 b[4];
      #pragma unroll
      for (int nt = 0; nt < 4; ++nt) {
        int n = wn * 64 + nt * 16 + l15;
        b[nt] = *(const bf16x8*)(p.Wt0 + (size_t)n * K0 + k);
      }
      #pragma unroll
      for (int mt = 0; mt < 2; ++mt)
        #pragma unroll
        for (int nt = 0; nt < 4; ++nt)
          acc[mt][nt] = __builtin_amdgcn_mfma_f32_16x16x32_bf16(a[mt], b[nt], acc[mt][nt], 0, 0, 0);
    }

    if constexpr (MODE == 3) {
      // decoder: relu(h)·decW1 reduce, diag overwrite
      float part[2][4] = {};
      #pragma unroll
      for (int mt = 0; mt < 2; ++mt) {
        #pragma unroll
        for (int nt = 0; nt < 4; ++nt) {
          int colb = wn * 64 + nt * 16 + l15;
          float w1 = p.decW1[colb];
          float bb = p.b0[colb];
          #pragma unroll
          for (int r = 0; r < 4; ++r)
            part[mt][r] += fmaxf(acc[mt][nt][r] + bb, 0.0f) * w1;
        }
      }
      #pragma unroll
      for (int mt = 0; mt < 2; ++mt) {
        #pragma unroll
        for (int r = 0; r < 4; ++r) {
          float v = part[mt][r];
          #pragma unroll
          for (int off = 1; off < 16; off <<= 1) v += __shfl_xor(v, off, 64);
          if (l15 == 0) s_dec[wn][wm * 32 + mt * 16 + l4 * 4 + r] = v;
        }
      }
      __syncthreads();
      if (tid < 64) {
        int gm = row0 + tid;
        if (gm < M) {
          float v = s_dec[0][tid] + s_dec[1][tid] + p.decB1[0];
          if (s_row[tid] == s_col[tid]) v = 0.5f * sqrtf(p.edge_attr[gm]);
          p.dout[gm] = v;
        }
      }
      return;
    } else {
      // h = relu(acc + b0) -> LDS (XOR-swizzled)
      #pragma unroll
      for (int mt = 0; mt < 2; ++mt) {
        #pragma unroll
        for (int nt = 0; nt < 4; ++nt) {
          int colb = wn * 64 + nt * 16 + l15;
          float bb = p.b0[colb];
          #pragma unroll
          for (int r = 0; r < 4; ++r) {
            int rowb = wm * 32 + mt * 16 + l4 * 4 + r;
            float v = fmaxf(acc[mt][nt][r] + bb, 0.0f);
            h_lds[rowb * 128 + (colb ^ ((rowb & 7) << 3))] = f2bf(v);
          }
        }
      }
    }
  }

  if constexpr (MODE != 3) {
    __syncthreads();
    // layer1: out = h @ W1 + b1
    f32x4 acc1[2][4] = {};
    #pragma unroll
    for (int ks = 0; ks < 4; ++ks) {
      const int k = ks * 32 + l4 * 8;
      bf16x8 a1[2];
      #pragma unroll
      for (int mt = 0; mt < 2; ++mt) {
        int rowb = wm * 32 + mt * 16 + l15;
        a1[mt] = *(const bf16x8*)&h_lds[rowb * 128 + (k ^ ((rowb & 7) << 3))];
      }
      bf16x8 b1v[4];
      #pragma unroll
      for (int nt = 0; nt < 4; ++nt) {
        int n = wn * 64 + nt * 16 + l15;
        b1v[nt] = *(const bf16x8*)(p.Wt1 + (size_t)n * 128 + k);
      }
      #pragma unroll
      for (int mt = 0; mt < 2; ++mt)
        #pragma unroll
        for (int nt = 0; nt < 4; ++nt)
          acc1[mt][nt] = __builtin_amdgcn_mfma_f32_16x16x32_bf16(a1[mt], b1v[nt], acc1[mt][nt], 0, 0, 0);
    }
    #pragma unroll
    for (int mt = 0; mt < 2; ++mt) {
      #pragma unroll
      for (int nt = 0; nt < 4; ++nt) {
        int colb = wn * 64 + nt * 16 + l15;
        float bb = p.b1[colb];
        #pragma unroll
        for (int r = 0; r < 4; ++r) {
          int rowb = wm * 32 + mt * 16 + l4 * 4 + r;
          int gm = row0 + rowb;
          if (gm < M) {
            float v = acc1[mt][nt][r] + bb;
            p.outB[(size_t)gm * 128 + colb] = f2bf(v);
          }
        }
      }
    }
  }
}

struct TransDesc { const float* src[16]; unsigned short* dst[16]; int K[16]; };

__global__ void trans_kernel(TransDesc td) {
  int m = blockIdx.y;
  int k = blockIdx.x;
  if (k >= td.K[m]) return;
  int n = threadIdx.x;  // 128
  td.dst[m][(size_t)n * td.K[m] + k] = f2bf(td.src[m][(size_t)k * 128 + n]);
}

__global__ void deg_kernel(const int* __restrict__ row, int E, int* cnt) {
  int i = blockIdx.x * blockDim.x + threadIdx.x;
  if (i < E) atomicAdd(&cnt[row[i]], 1);
}

__global__ void invcnt_kernel(const int* __restrict__ cnt, int N, float* inv) {
  int i = blockIdx.x * blockDim.x + threadIdx.x;
  if (i < N) { int c = cnt[i]; inv[i] = 1.0f / (float)(c > 1 ? c : 1); }
}

// single-block exclusive scan of cnt[N] -> offs, cursor
__global__ __launch_bounds__(1024) void scan_kernel(const int* __restrict__ cnt, int N,
                                                    int* __restrict__ offs, int* __restrict__ cursor) {
  __shared__ int lds[1024];
  __shared__ int carry;
  if (threadIdx.x == 0) carry = 0;
  __syncthreads();
  for (int base = 0; base < N; base += 1024) {
    int i = base + (int)threadIdx.x;
    int v = (i < N) ? cnt[i] : 0;
    lds[threadIdx.x] = v;
    __syncthreads();
    #pragma unroll
    for (int off = 1; off < 1024; off <<= 1) {
      int t = (threadIdx.x >= (unsigned)off) ? lds[threadIdx.x - off] : 0;
      __syncthreads();
      lds[threadIdx.x] += t;
      __syncthreads();
    }
    int excl = lds[threadIdx.x] - v + carry;
    if (i < N) { offs[i] = excl; cursor[i] = excl; }
    __syncthreads();
    if (threadIdx.x == 1023) carry += lds[1023];
    __syncthreads();
  }
}

__global__ void scatter_kernel(const int* __restrict__ row, int E,
                               int* __restrict__ cursor, int* __restrict__ eid) {
  int i = blockIdx.x * blockDim.x + threadIdx.x;
  if (i < E) {
    int r = row[i];
    int pos = atomicAdd(&cursor[r], 1);
    eid[pos] = i;
  }
}

// CSR gather-sum aggregation: 4 nodes per block (1 wave each), fused mean + bf16 cast
__global__ __launch_bounds__(256) void agg_kernel(const unsigned short* __restrict__ le,
                                                  const int* __restrict__ offs,
                                                  const int* __restrict__ cnt,
                                                  const float* __restrict__ inv,
                                                  const int* __restrict__ eid,
                                                  unsigned short* __restrict__ aggb, int N) {
  int wave = threadIdx.x >> 6, lane = threadIdx.x & 63;
  int n = blockIdx.x * 4 + wave;
  if (n >= N) return;
  int beg = offs[n], d = cnt[n];
  float sx0 = 0, sy0 = 0, sx1 = 0, sy1 = 0;
  int j = 0;
  for (; j + 1 < d; j += 2) {
    int e0 = eid[beg + j], e1 = eid[beg + j + 1];
    ushort2 v0 = *(const ushort2*)(le + (size_t)e0 * 128 + lane * 2);
    ushort2 v1 = *(const ushort2*)(le + (size_t)e1 * 128 + lane * 2);
    sx0 += bf2f(v0.x); sy0 += bf2f(v0.y);
    sx1 += bf2f(v1.x); sy1 += bf2f(v1.y);
  }
  if (j < d) {
    int e0 = eid[beg + j];
    ushort2 v0 = *(const ushort2*)(le + (size_t)e0 * 128 + lane * 2);
    sx0 += bf2f(v0.x); sy0 += bf2f(v0.y);
  }
  float iv = inv[n];
  ushort2 o;
  o.x = f2bf((sx0 + sx1) * iv);
  o.y = f2bf((sy0 + sy1) * iv);
  *(ushort2*)(aggb + (size_t)n * 128 + lane * 2) = o;
}

extern "C" void kernel_launch(void* const* d_in, const int* in_sizes, int n_in,
                              void* d_out, int out_size, void* d_ws, size_t ws_size,
                              hipStream_t stream) {
  const float* x         = (const float*)d_in[0];
  const float* edge_attr = (const float*)d_in[1];
  const int*   eidx      = (const int*)  d_in[2];
  const float* encn_W0 = (const float*)d_in[3];
  const float* encn_b0 = (const float*)d_in[4];
  const float* encn_W1 = (const float*)d_in[5];
  const float* encn_b1 = (const float*)d_in[6];
  const float* ence_W0 = (const float*)d_in[7];
  const float* ence_b0 = (const float*)d_in[8];
  const float* ence_W1 = (const float*)d_in[9];
  const float* ence_b1 = (const float*)d_in[10];
  const float* dec_W0  = (const float*)d_in[11];
  const float* dec_b0  = (const float*)d_in[12];
  const float* dec_W1  = (const float*)d_in[13];
  const float* dec_b1  = (const float*)d_in[14];
  const float* eW0 = (const float*)d_in[15];
  const float* eb0 = (const float*)d_in[16];
  const float* eW1 = (const float*)d_in[17];
  const float* eb1 = (const float*)d_in[18];
  const float* nW0 = (const float*)d_in[19];
  const float* nb0 = (const float*)d_in[20];
  const float* nW1 = (const float*)d_in[21];
  const float* nb1 = (const float*)d_in[22];

  const int N = in_sizes[0];
  const int E = in_sizes[1];
  const int* rowI = eidx;
  const int* colI = eidx + E;

  char* w = (char*)d_ws;
  auto take = [&](size_t bytes) -> char* {
    char* p = w; w += (bytes + 255) & ~(size_t)255; return p;
  };
  unsigned short* ln   = (unsigned short*)take((size_t)N * 128 * 2);
  unsigned short* le   = (unsigned short*)take((size_t)E * 128 * 2);
  unsigned short* aggb = (unsigned short*)take((size_t)N * 128 * 2);
  int*            cnt  = (int*)take((size_t)N * 4);
  float*          inv  = (float*)take((size_t)N * 4);
  int*            offs = (int*)take((size_t)N * 4);
  int*            curs = (int*)take((size_t)N * 4);
  int*            eidArr = (int*)take((size_t)E * 4);
  unsigned short* wt_encn1 = (unsigned short*)take(128 * 128 * 2);
  unsigned short* wt_ence1 = (unsigned short*)take(128 * 128 * 2);
  unsigned short* wt_dec0  = (unsigned short*)take(128 * 128 * 2);
  unsigned short *wt_e0[3], *wt_e1[3], *wt_n0[3], *wt_n1[3];
  for (int s = 0; s < 3; ++s) wt_e0[s] = (unsigned short*)take(384 * 128 * 2);
  for (int s = 0; s < 3; ++s) wt_e1[s] = (unsigned short*)take(128 * 128 * 2);
  for (int s = 0; s < 3; ++s) wt_n0[s] = (unsigned short*)take(256 * 128 * 2);
  for (int s = 0; s < 3; ++s) wt_n1[s] = (unsigned short*)take(128 * 128 * 2);

  TransDesc td{};
  int mi = 0;
  auto add = [&](const float* s, unsigned short* d, int K) {
    td.src[mi] = s; td.dst[mi] = d; td.K[mi] = K; ++mi;
  };
  add(encn_W1, wt_encn1, 128);
  add(ence_W1, wt_ence1, 128);
  add(dec_W0,  wt_dec0,  128);
  for (int s = 0; s < 3; ++s) add(eW0 + (size_t)s * 384 * 128, wt_e0[s], 384);
  for (int s = 0; s < 3; ++s) add(eW1 + (size_t)s * 128 * 128, wt_e1[s], 128);
  for (int s = 0; s < 3; ++s) add(nW0 + (size_t)s * 256 * 128, wt_n0[s], 256);
  for (int s = 0; s < 3; ++s) add(nW1 + (size_t)s * 128 * 128, wt_n1[s], 128);

  hipMemsetAsync(cnt, 0, (size_t)N * 4, stream);
  trans_kernel<<<dim3(384, mi), 128, 0, stream>>>(td);
  deg_kernel<<<(E + 255) / 256, 256, 0, stream>>>(rowI, E, cnt);
  invcnt_kernel<<<(N + 255) / 256, 256, 0, stream>>>(cnt, N, inv);
  scan_kernel<<<1, 1024, 0, stream>>>(cnt, N, offs, curs);
  scatter_kernel<<<(E + 255) / 256, 256, 0, stream>>>(rowI, E, curs, eidArr);

  {
    MlpParams q{}; q.M = N; q.x = x; q.W0v = encn_W0; q.b0 = encn_b0;
    q.Wt1 = wt_encn1; q.b1 = encn_b1; q.outB = ln;
    mlp_kernel<0, 128><<<(N + 63) / 64, 256, 0, stream>>>(q);
  }
  {
    MlpParams q{}; q.M = E; q.x = edge_attr; q.W0v = ence_W0; q.b0 = ence_b0;
    q.Wt1 = wt_ence1; q.b1 = ence_b1; q.outB = le;
    mlp_kernel<0, 128><<<(E + 63) / 64, 256, 0, stream>>>(q);
  }

  for (int s = 0; s < 3; ++s) {
    {
      MlpParams q{}; q.M = E; q.ln = ln; q.src2 = le; q.rowIdx = rowI; q.colIdx = colI;
      q.Wt0 = wt_e0[s]; q.b0 = eb0 + s * 128; q.Wt1 = wt_e1[s]; q.b1 = eb1 + s * 128;
      q.outB = le;
      mlp_kernel<1, 384><<<(E + 63) / 64, 256, 0, stream>>>(q);
    }
    agg_kernel<<<(N + 3) / 4, 256, 0, stream>>>(le, offs, cnt, inv, eidArr, aggb, N);
    {
      MlpParams q{}; q.M = N; q.ln = ln; q.src2 = aggb;
      q.Wt0 = wt_n0[s]; q.b0 = nb0 + s * 128; q.Wt1 = wt_n1[s]; q.b1 = nb1 + s * 128;
      q.outB = ln;
      mlp_kernel<2, 256><<<(N + 63) / 64, 256, 0, stream>>>(q);
    }
  }
  {
    MlpParams q{}; q.M = E; q.ln = le; q.rowIdx = rowI; q.colIdx = colI;
    q.Wt0 = wt_dec0; q.b0 = dec_b0; q.decW1 = dec_W1; q.decB1 = dec_b1;
    q.edge_attr = edge_attr; q.dout = (float*)d_out;
    mlp_kernel<3, 128><<<(E + 63) / 64, 256, 0, stream>>>(q);
  }
}

// Round 3
// 944.161 us; speedup vs baseline: 1.0990x; 1.0490x over previous
//
#include <hip/hip_runtime.h>
#include <hip/hip_bf16.h>
#include <stdint.h>

typedef __attribute__((ext_vector_type(8))) short bf16x8;
typedef __attribute__((ext_vector_type(4))) float f32x4;

__device__ __forceinline__ unsigned short f2bf(float f) {
  union { float f; uint32_t u; } c; c.f = f;
  uint32_t r = (c.u + 0x7FFFu + ((c.u >> 16) & 1u)) >> 16;
  return (unsigned short)r;
}
__device__ __forceinline__ float bf2f(unsigned short u) {
  union { uint32_t u; float f; } c; c.u = (uint32_t)u << 16; return c.f;
}

struct MlpParams {
  int M;
  const unsigned short* ln;    // gather source A (EDGE/NODE: ln; DEC: le)
  const unsigned short* src2;  // EDGE: le; NODE: aggb
  const int* rowIdx;           // EDGE/DEC: row_p
  const int* colIdx;           // EDGE/DEC: col_p
  const int* eid;              // DEC: scatter target index
  const float* x;              // ENC scalar input (node x, or ea_p)
  const float* W0v;            // ENC layer0 weight [128]
  const unsigned short* Wt0;   // [128][K0] bf16
  const float* b0;
  const unsigned short* Wt1;   // [128][128] bf16
  const float* b1;
  unsigned short* outB;
  const float* decW1;
  const float* decB1;
  const float* edge_attr;      // DEC: ea_p
  float* dout;
};

// MODE: 0=ENC(scalar layer0), 1=EDGE(concat3), 2=NODE(concat2), 3=DEC
template<int MODE, int K0>
__global__ __launch_bounds__(256) void mlp_kernel(MlpParams p) {
  __shared__ __align__(16) unsigned short h_lds[64 * 128];
  __shared__ int s_row[64], s_col[64];
  __shared__ float s_dec[2][64];

  const int tid = threadIdx.x;
  const int wave = tid >> 6, lane = tid & 63;
  const int wm = wave >> 1, wn = wave & 1;
  const int l15 = lane & 15, l4 = lane >> 4;
  const int row0 = blockIdx.x * 64;
  const int M = p.M;

  if constexpr (MODE == 1 || MODE == 3) {
    if (tid < 64) {
      int e = row0 + tid; if (e > M - 1) e = M - 1;
      s_row[tid] = p.rowIdx[e];
      s_col[tid] = p.colIdx[e];
    }
    __syncthreads();
  }

  if constexpr (MODE == 0) {
    // layer0: h = relu(x * W0 + b0), rank-1, computed directly in C-layout
    #pragma unroll
    for (int mt = 0; mt < 2; ++mt) {
      #pragma unroll
      for (int r = 0; r < 4; ++r) {
        int rowb = wm * 32 + mt * 16 + l4 * 4 + r;
        int gm = row0 + rowb; if (gm > M - 1) gm = M - 1;
        float xv = p.x[gm];
        #pragma unroll
        for (int nt = 0; nt < 4; ++nt) {
          int colb = wn * 64 + nt * 16 + l15;
          float v = fmaxf(xv * p.W0v[colb] + p.b0[colb], 0.0f);
          h_lds[rowb * 128 + (colb ^ ((rowb & 7) << 3))] = f2bf(v);
        }
      }
    }
  } else {
    f32x4 acc[2][4] = {};
    #pragma unroll
    for (int ks = 0; ks < K0 / 32; ++ks) {
      const int k = ks * 32 + l4 * 8;
      bf16x8 a[2];
      #pragma unroll
      for (int mt = 0; mt < 2; ++mt) {
        int m_loc = wm * 32 + mt * 16 + l15;
        int gm = row0 + m_loc; if (gm > M - 1) gm = M - 1;
        const unsigned short* sp;
        if constexpr (MODE == 1) {
          if (k < 128)      sp = p.ln   + (size_t)s_row[m_loc] * 128 + k;
          else if (k < 256) sp = p.ln   + (size_t)s_col[m_loc] * 128 + (k - 128);
          else              sp = p.src2 + (size_t)gm * 128 + (k - 256);
        } else if constexpr (MODE == 2) {
          if (k < 128)      sp = p.ln   + (size_t)gm * 128 + k;
          else              sp = p.src2 + (size_t)gm * 128 + (k - 128);
        } else {
          sp = p.ln + (size_t)gm * 128 + k;
        }
        a[mt] = *(const bf16x8*)sp;
      }
      bf16x8 b[4];
      #pragma unroll
      for (int nt = 0; nt < 4; ++nt) {
        int n = wn * 64 + nt * 16 + l15;
        b[nt] = *(const bf16x8*)(p.Wt0 + (size_t)n * K0 + k);
      }
      #pragma unroll
      for (int mt = 0; mt < 2; ++mt)
        #pragma unroll
        for (int nt = 0; nt < 4; ++nt)
          acc[mt][nt] = __builtin_amdgcn_mfma_f32_16x16x32_bf16(a[mt], b[nt], acc[mt][nt], 0, 0, 0);
    }

    if constexpr (MODE == 3) {
      // decoder: relu(h)·decW1 reduce, diag overwrite, scatter store
      float part[2][4] = {};
      #pragma unroll
      for (int mt = 0; mt < 2; ++mt) {
        #pragma unroll
        for (int nt = 0; nt < 4; ++nt) {
          int colb = wn * 64 + nt * 16 + l15;
          float w1 = p.decW1[colb];
          float bb = p.b0[colb];
          #pragma unroll
          for (int r = 0; r < 4; ++r)
            part[mt][r] += fmaxf(acc[mt][nt][r] + bb, 0.0f) * w1;
        }
      }
      #pragma unroll
      for (int mt = 0; mt < 2; ++mt) {
        #pragma unroll
        for (int r = 0; r < 4; ++r) {
          float v = part[mt][r];
          #pragma unroll
          for (int off = 1; off < 16; off <<= 1) v += __shfl_xor(v, off, 64);
          if (l15 == 0) s_dec[wn][wm * 32 + mt * 16 + l4 * 4 + r] = v;
        }
      }
      __syncthreads();
      if (tid < 64) {
        int gm = row0 + tid;
        if (gm < M) {
          float v = s_dec[0][tid] + s_dec[1][tid] + p.decB1[0];
          if (s_row[tid] == s_col[tid]) v = 0.5f * sqrtf(p.edge_attr[gm]);
          p.dout[p.eid[gm]] = v;
        }
      }
      return;
    } else {
      // h = relu(acc + b0) -> LDS (XOR-swizzled)
      #pragma unroll
      for (int mt = 0; mt < 2; ++mt) {
        #pragma unroll
        for (int nt = 0; nt < 4; ++nt) {
          int colb = wn * 64 + nt * 16 + l15;
          float bb = p.b0[colb];
          #pragma unroll
          for (int r = 0; r < 4; ++r) {
            int rowb = wm * 32 + mt * 16 + l4 * 4 + r;
            float v = fmaxf(acc[mt][nt][r] + bb, 0.0f);
            h_lds[rowb * 128 + (colb ^ ((rowb & 7) << 3))] = f2bf(v);
          }
        }
      }
    }
  }

  if constexpr (MODE != 3) {
    __syncthreads();
    // layer1: out = h @ W1 + b1
    f32x4 acc1[2][4] = {};
    #pragma unroll
    for (int ks = 0; ks < 4; ++ks) {
      const int k = ks * 32 + l4 * 8;
      bf16x8 a1[2];
      #pragma unroll
      for (int mt = 0; mt < 2; ++mt) {
        int rowb = wm * 32 + mt * 16 + l15;
        a1[mt] = *(const bf16x8*)&h_lds[rowb * 128 + (k ^ ((rowb & 7) << 3))];
      }
      bf16x8 b1v[4];
      #pragma unroll
      for (int nt = 0; nt < 4; ++nt) {
        int n = wn * 64 + nt * 16 + l15;
        b1v[nt] = *(const bf16x8*)(p.Wt1 + (size_t)n * 128 + k);
      }
      #pragma unroll
      for (int mt = 0; mt < 2; ++mt)
        #pragma unroll
        for (int nt = 0; nt < 4; ++nt)
          acc1[mt][nt] = __builtin_amdgcn_mfma_f32_16x16x32_bf16(a1[mt], b1v[nt], acc1[mt][nt], 0, 0, 0);
    }
    #pragma unroll
    for (int mt = 0; mt < 2; ++mt) {
      #pragma unroll
      for (int nt = 0; nt < 4; ++nt) {
        int colb = wn * 64 + nt * 16 + l15;
        float bb = p.b1[colb];
        #pragma unroll
        for (int r = 0; r < 4; ++r) {
          int rowb = wm * 32 + mt * 16 + l4 * 4 + r;
          int gm = row0 + rowb;
          if (gm < M) {
            float v = acc1[mt][nt][r] + bb;
            p.outB[(size_t)gm * 128 + colb] = f2bf(v);
          }
        }
      }
    }
  }
}

struct TransDesc { const float* src[16]; unsigned short* dst[16]; int K[16]; };

__global__ void trans_kernel(TransDesc td) {
  int m = blockIdx.y;
  int k = blockIdx.x;
  if (k >= td.K[m]) return;
  int n = threadIdx.x;  // 128
  td.dst[m][(size_t)n * td.K[m] + k] = f2bf(td.src[m][(size_t)k * 128 + n]);
}

__global__ void deg_kernel(const int* __restrict__ row, int E, int* cnt) {
  int i = blockIdx.x * blockDim.x + threadIdx.x;
  if (i < E) atomicAdd(&cnt[row[i]], 1);
}

__global__ void invcnt_kernel(const int* __restrict__ cnt, int N, float* inv) {
  int i = blockIdx.x * blockDim.x + threadIdx.x;
  if (i < N) { int c = cnt[i]; inv[i] = 1.0f / (float)(c > 1 ? c : 1); }
}

// single-block exclusive scan of cnt[N] -> offs, cursor
__global__ __launch_bounds__(1024) void scan_kernel(const int* __restrict__ cnt, int N,
                                                    int* __restrict__ offs, int* __restrict__ cursor) {
  __shared__ int lds[1024];
  __shared__ int carry;
  if (threadIdx.x == 0) carry = 0;
  __syncthreads();
  for (int base = 0; base < N; base += 1024) {
    int i = base + (int)threadIdx.x;
    int v = (i < N) ? cnt[i] : 0;
    lds[threadIdx.x] = v;
    __syncthreads();
    #pragma unroll
    for (int off = 1; off < 1024; off <<= 1) {
      int t = (threadIdx.x >= (unsigned)off) ? lds[threadIdx.x - off] : 0;
      __syncthreads();
      lds[threadIdx.x] += t;
      __syncthreads();
    }
    int excl = lds[threadIdx.x] - v + carry;
    if (i < N) { offs[i] = excl; cursor[i] = excl; }
    __syncthreads();
    if (threadIdx.x == 1023) carry += lds[1023];
    __syncthreads();
  }
}

__global__ void scatter_kernel(const int* __restrict__ row, int E,
                               int* __restrict__ cursor, int* __restrict__ eid) {
  int i = blockIdx.x * blockDim.x + threadIdx.x;
  if (i < E) {
    int r = row[i];
    int pos = atomicAdd(&cursor[r], 1);
    eid[pos] = i;
  }
}

// build permuted row/col/edge_attr in CSR order
__global__ void permute_kernel(const int* __restrict__ eid,
                               const int* __restrict__ row, const int* __restrict__ col,
                               const float* __restrict__ ea, int E,
                               int* __restrict__ row_p, int* __restrict__ col_p,
                               float* __restrict__ ea_p) {
  int i = blockIdx.x * blockDim.x + threadIdx.x;
  if (i < E) {
    int e = eid[i];
    row_p[i] = row[e];
    col_p[i] = col[e];
    ea_p[i]  = ea[e];
  }
}

// CSR contiguous-range aggregation over permuted le: 4 nodes/block (1 wave each)
__global__ __launch_bounds__(256) void agg_kernel(const unsigned short* __restrict__ le,
                                                  const int* __restrict__ offs,
                                                  const int* __restrict__ cnt,
                                                  const float* __restrict__ inv,
                                                  unsigned short* __restrict__ aggb, int N) {
  int wave = threadIdx.x >> 6, lane = threadIdx.x & 63;
  int n = blockIdx.x * 4 + wave;
  if (n >= N) return;
  int beg = offs[n], d = cnt[n];
  const unsigned short* base = le + (size_t)beg * 128 + lane * 2;
  float sx0 = 0, sy0 = 0, sx1 = 0, sy1 = 0;
  int j = 0;
  for (; j + 1 < d; j += 2) {
    ushort2 v0 = *(const ushort2*)(base + (size_t)j * 128);
    ushort2 v1 = *(const ushort2*)(base + (size_t)(j + 1) * 128);
    sx0 += bf2f(v0.x); sy0 += bf2f(v0.y);
    sx1 += bf2f(v1.x); sy1 += bf2f(v1.y);
  }
  if (j < d) {
    ushort2 v0 = *(const ushort2*)(base + (size_t)j * 128);
    sx0 += bf2f(v0.x); sy0 += bf2f(v0.y);
  }
  float iv = inv[n];
  ushort2 o;
  o.x = f2bf((sx0 + sx1) * iv);
  o.y = f2bf((sy0 + sy1) * iv);
  *(ushort2*)(aggb + (size_t)n * 128 + lane * 2) = o;
}

extern "C" void kernel_launch(void* const* d_in, const int* in_sizes, int n_in,
                              void* d_out, int out_size, void* d_ws, size_t ws_size,
                              hipStream_t stream) {
  const float* x         = (const float*)d_in[0];
  const float* edge_attr = (const float*)d_in[1];
  const int*   eidx      = (const int*)  d_in[2];
  const float* encn_W0 = (const float*)d_in[3];
  const float* encn_b0 = (const float*)d_in[4];
  const float* encn_W1 = (const float*)d_in[5];
  const float* encn_b1 = (const float*)d_in[6];
  const float* ence_W0 = (const float*)d_in[7];
  const float* ence_b0 = (const float*)d_in[8];
  const float* ence_W1 = (const float*)d_in[9];
  const float* ence_b1 = (const float*)d_in[10];
  const float* dec_W0  = (const float*)d_in[11];
  const float* dec_b0  = (const float*)d_in[12];
  const float* dec_W1  = (const float*)d_in[13];
  const float* dec_b1  = (const float*)d_in[14];
  const float* eW0 = (const float*)d_in[15];
  const float* eb0 = (const float*)d_in[16];
  const float* eW1 = (const float*)d_in[17];
  const float* eb1 = (const float*)d_in[18];
  const float* nW0 = (const float*)d_in[19];
  const float* nb0 = (const float*)d_in[20];
  const float* nW1 = (const float*)d_in[21];
  const float* nb1 = (const float*)d_in[22];

  const int N = in_sizes[0];
  const int E = in_sizes[1];
  const int* rowI = eidx;
  const int* colI = eidx + E;

  char* w = (char*)d_ws;
  auto take = [&](size_t bytes) -> char* {
    char* p = w; w += (bytes + 255) & ~(size_t)255; return p;
  };
  unsigned short* ln   = (unsigned short*)take((size_t)N * 128 * 2);
  unsigned short* le   = (unsigned short*)take((size_t)E * 128 * 2);  // permuted (CSR) order
  unsigned short* aggb = (unsigned short*)take((size_t)N * 128 * 2);
  int*            cnt  = (int*)take((size_t)N * 4);
  float*          inv  = (float*)take((size_t)N * 4);
  int*            offs = (int*)take((size_t)N * 4);
  int*            curs = (int*)take((size_t)N * 4);
  int*            eidArr = (int*)take((size_t)E * 4);
  int*            row_p  = (int*)take((size_t)E * 4);
  int*            col_p  = (int*)take((size_t)E * 4);
  float*          ea_p   = (float*)take((size_t)E * 4);
  unsigned short* wt_encn1 = (unsigned short*)take(128 * 128 * 2);
  unsigned short* wt_ence1 = (unsigned short*)take(128 * 128 * 2);
  unsigned short* wt_dec0  = (unsigned short*)take(128 * 128 * 2);
  unsigned short *wt_e0[3], *wt_e1[3], *wt_n0[3], *wt_n1[3];
  for (int s = 0; s < 3; ++s) wt_e0[s] = (unsigned short*)take(384 * 128 * 2);
  for (int s = 0; s < 3; ++s) wt_e1[s] = (unsigned short*)take(128 * 128 * 2);
  for (int s = 0; s < 3; ++s) wt_n0[s] = (unsigned short*)take(256 * 128 * 2);
  for (int s = 0; s < 3; ++s) wt_n1[s] = (unsigned short*)take(128 * 128 * 2);

  TransDesc td{};
  int mi = 0;
  auto add = [&](const float* s, unsigned short* d, int K) {
    td.src[mi] = s; td.dst[mi] = d; td.K[mi] = K; ++mi;
  };
  add(encn_W1, wt_encn1, 128);
  add(ence_W1, wt_ence1, 128);
  add(dec_W0,  wt_dec0,  128);
  for (int s = 0; s < 3; ++s) add(eW0 + (size_t)s * 384 * 128, wt_e0[s], 384);
  for (int s = 0; s < 3; ++s) add(eW1 + (size_t)s * 128 * 128, wt_e1[s], 128);
  for (int s = 0; s < 3; ++s) add(nW0 + (size_t)s * 256 * 128, wt_n0[s], 256);
  for (int s = 0; s < 3; ++s) add(nW1 + (size_t)s * 128 * 128, wt_n1[s], 128);

  hipMemsetAsync(cnt, 0, (size_t)N * 4, stream);
  trans_kernel<<<dim3(384, mi), 128, 0, stream>>>(td);
  deg_kernel<<<(E + 255) / 256, 256, 0, stream>>>(rowI, E, cnt);
  invcnt_kernel<<<(N + 255) / 256, 256, 0, stream>>>(cnt, N, inv);
  scan_kernel<<<1, 1024, 0, stream>>>(cnt, N, offs, curs);
  scatter_kernel<<<(E + 255) / 256, 256, 0, stream>>>(rowI, E, curs, eidArr);
  permute_kernel<<<(E + 255) / 256, 256, 0, stream>>>(eidArr, rowI, colI, edge_attr, E,
                                                      row_p, col_p, ea_p);

  {
    MlpParams q{}; q.M = N; q.x = x; q.W0v = encn_W0; q.b0 = encn_b0;
    q.Wt1 = wt_encn1; q.b1 = encn_b1; q.outB = ln;
    mlp_kernel<0, 128><<<(N + 63) / 64, 256, 0, stream>>>(q);
  }
  {
    // edge encoder reads permuted edge_attr, writes permuted le
    MlpParams q{}; q.M = E; q.x = ea_p; q.W0v = ence_W0; q.b0 = ence_b0;
    q.Wt1 = wt_ence1; q.b1 = ence_b1; q.outB = le;
    mlp_kernel<0, 128><<<(E + 63) / 64, 256, 0, stream>>>(q);
  }

  for (int s = 0; s < 3; ++s) {
    {
      MlpParams q{}; q.M = E; q.ln = ln; q.src2 = le; q.rowIdx = row_p; q.colIdx = col_p;
      q.Wt0 = wt_e0[s]; q.b0 = eb0 + s * 128; q.Wt1 = wt_e1[s]; q.b1 = eb1 + s * 128;
      q.outB = le;
      mlp_kernel<1, 384><<<(E + 63) / 64, 256, 0, stream>>>(q);
    }
    agg_kernel<<<(N + 3) / 4, 256, 0, stream>>>(le, offs, cnt, inv, aggb, N);
    {
      MlpParams q{}; q.M = N; q.ln = ln; q.src2 = aggb;
      q.Wt0 = wt_n0[s]; q.b0 = nb0 + s * 128; q.Wt1 = wt_n1[s]; q.b1 = nb1 + s * 128;
      q.outB = ln;
      mlp_kernel<2, 256><<<(N + 63) / 64, 256, 0, stream>>>(q);
    }
  }
  {
    MlpParams q{}; q.M = E; q.ln = le; q.rowIdx = row_p; q.colIdx = col_p; q.eid = eidArr;
    q.Wt0 = wt_dec0; q.b0 = dec_b0; q.decW1 = dec_W1; q.decB1 = dec_b1;
    q.edge_attr = ea_p; q.dout = (float*)d_out;
    mlp_kernel<3, 128><<<(E + 63) / 64, 256, 0, stream>>>(q);
  }
}

// Round 4
// 897.208 us; speedup vs baseline: 1.1565x; 1.0523x over previous
//
#include <hip/hip_runtime.h>
#include <hip/hip_bf16.h>
#include <stdint.h>

typedef __attribute__((ext_vector_type(8))) short bf16x8;
typedef __attribute__((ext_vector_type(4))) float f32x4;

__device__ __forceinline__ unsigned short f2bf(float f) {
  union { float f; uint32_t u; } c; c.f = f;
  uint32_t r = (c.u + 0x7FFFu + ((c.u >> 16) & 1u)) >> 16;
  return (unsigned short)r;
}
__device__ __forceinline__ float bf2f(unsigned short u) {
  union { uint32_t u; float f; } c; c.u = (uint32_t)u << 16; return c.f;
}

__device__ __forceinline__ void gload_lds16(const void* g, void* l) {
  __builtin_amdgcn_global_load_lds((const __attribute__((address_space(1))) void*)g,
                                   (__attribute__((address_space(3))) void*)l, 16, 0, 0);
}

struct MlpParams {
  int M;
  const unsigned short* ln;    // gather source A (EDGE/NODE: ln; DEC: le)
  const unsigned short* src2;  // EDGE: le; NODE: aggb
  const int* rowIdx;           // EDGE/DEC: row_p
  const int* colIdx;           // EDGE/DEC: col_p
  const int* eid;              // DEC: scatter target index
  const float* x;              // ENC scalar input (node x, or ea_p)
  const float* W0v;            // ENC layer0 weight [128]
  const unsigned short* Wt0;   // [128][K0] bf16
  const float* b0;
  const unsigned short* Wt1;   // [128][128] bf16
  const float* b1;
  unsigned short* outB;
  const float* decW1;
  const float* decB1;
  const float* edge_attr;      // DEC: ea_p
  float* dout;
};

// MODE: 0=ENC(scalar layer0), 1=EDGE(concat3, async-LDS-staged A), 2=NODE(concat2), 3=DEC
template<int MODE, int K0>
__global__ __launch_bounds__(256) void mlp_kernel(MlpParams p) {
  constexpr int NSEG = (MODE == 1) ? 3 : 1;
  __shared__ __align__(16) unsigned short a_lds[NSEG][64 * 128];  // [0] doubles as h-tile
  __shared__ int s_row[64], s_col[64];
  __shared__ float s_dec[2][64];

  const int tid = threadIdx.x;
  const int wave = tid >> 6, lane = tid & 63;
  const int wm = wave >> 1, wn = wave & 1;
  const int l15 = lane & 15, l4 = lane >> 4;
  const int row0 = blockIdx.x * 64;
  const int M = p.M;

  if constexpr (MODE == 1 || MODE == 3) {
    if (tid < 64) {
      int e = row0 + tid; if (e > M - 1) e = M - 1;
      s_row[tid] = p.rowIdx[e];
      s_col[tid] = p.colIdx[e];
    }
    __syncthreads();
  }

  if constexpr (MODE == 1) {
    // Async gather-stage the whole [64 x 384] A-tile into LDS:
    // seg0 = ln[row], seg1 = ln[col], seg2 = le (contiguous).
    // LDS dest is linear (HW: base + lane*16); the 16B-chunk index is
    // pre-swizzled on the GLOBAL source (j ^ (row&7)) and the ds_read
    // applies the same XOR -> conflict-free reads (rule #21).
    const int jj = lane & 15;
    #pragma unroll
    for (int i = 0; i < 4; ++i) {
      int rowl = 16 * wave + 4 * i + (lane >> 4);
      int gm = row0 + rowl; if (gm > M - 1) gm = M - 1;
      int sw = (jj ^ (rowl & 7)) * 8;
      const unsigned short* s0 = p.ln   + (size_t)s_row[rowl] * 128 + sw;
      const unsigned short* s1 = p.ln   + (size_t)s_col[rowl] * 128 + sw;
      const unsigned short* s2 = p.src2 + (size_t)gm * 128 + sw;
      unsigned short* dbase0 = &a_lds[0][(16 * wave + 4 * i) * 128];
      unsigned short* dbase1 = &a_lds[1][(16 * wave + 4 * i) * 128];
      unsigned short* dbase2 = &a_lds[2][(16 * wave + 4 * i) * 128];
      gload_lds16(s0, dbase0);
      gload_lds16(s1, dbase1);
      gload_lds16(s2, dbase2);
    }
    __syncthreads();  // drains vmcnt (all 12 staging loads) + barrier
  }

  if constexpr (MODE == 0) {
    // layer0: h = relu(x * W0 + b0), rank-1, computed directly in C-layout
    #pragma unroll
    for (int mt = 0; mt < 2; ++mt) {
      #pragma unroll
      for (int r = 0; r < 4; ++r) {
        int rowb = wm * 32 + mt * 16 + l4 * 4 + r;
        int gm = row0 + rowb; if (gm > M - 1) gm = M - 1;
        float xv = p.x[gm];
        #pragma unroll
        for (int nt = 0; nt < 4; ++nt) {
          int colb = wn * 64 + nt * 16 + l15;
          float v = fmaxf(xv * p.W0v[colb] + p.b0[colb], 0.0f);
          a_lds[0][rowb * 128 + (colb ^ ((rowb & 7) << 3))] = f2bf(v);
        }
      }
    }
  } else {
    f32x4 acc[2][4] = {};
    #pragma unroll
    for (int ks = 0; ks < K0 / 32; ++ks) {
      const int k = ks * 32 + l4 * 8;
      bf16x8 a[2];
      #pragma unroll
      for (int mt = 0; mt < 2; ++mt) {
        int m_loc = wm * 32 + mt * 16 + l15;
        if constexpr (MODE == 1) {
          int seg = ks >> 2, kq = ks & 3;
          int slot = ((kq << 2) + l4) ^ (m_loc & 7);
          a[mt] = *(const bf16x8*)&a_lds[seg][m_loc * 128 + slot * 8];
        } else {
          int gm = row0 + m_loc; if (gm > M - 1) gm = M - 1;
          const unsigned short* sp;
          if constexpr (MODE == 2) {
            if (k < 128)      sp = p.ln   + (size_t)gm * 128 + k;
            else              sp = p.src2 + (size_t)gm * 128 + (k - 128);
          } else {
            sp = p.ln + (size_t)gm * 128 + k;
          }
          a[mt] = *(const bf16x8*)sp;
        }
      }
      bf16x8 b[4];
      #pragma unroll
      for (int nt = 0; nt < 4; ++nt) {
        int n = wn * 64 + nt * 16 + l15;
        b[nt] = *(const bf16x8*)(p.Wt0 + (size_t)n * K0 + k);
      }
      #pragma unroll
      for (int mt = 0; mt < 2; ++mt)
        #pragma unroll
        for (int nt = 0; nt < 4; ++nt)
          acc[mt][nt] = __builtin_amdgcn_mfma_f32_16x16x32_bf16(a[mt], b[nt], acc[mt][nt], 0, 0, 0);
    }

    if constexpr (MODE == 3) {
      // decoder: relu(h)·decW1 reduce, diag overwrite, scatter store
      float part[2][4] = {};
      #pragma unroll
      for (int mt = 0; mt < 2; ++mt) {
        #pragma unroll
        for (int nt = 0; nt < 4; ++nt) {
          int colb = wn * 64 + nt * 16 + l15;
          float w1 = p.decW1[colb];
          float bb = p.b0[colb];
          #pragma unroll
          for (int r = 0; r < 4; ++r)
            part[mt][r] += fmaxf(acc[mt][nt][r] + bb, 0.0f) * w1;
        }
      }
      #pragma unroll
      for (int mt = 0; mt < 2; ++mt) {
        #pragma unroll
        for (int r = 0; r < 4; ++r) {
          float v = part[mt][r];
          #pragma unroll
          for (int off = 1; off < 16; off <<= 1) v += __shfl_xor(v, off, 64);
          if (l15 == 0) s_dec[wn][wm * 32 + mt * 16 + l4 * 4 + r] = v;
        }
      }
      __syncthreads();
      if (tid < 64) {
        int gm = row0 + tid;
        if (gm < M) {
          float v = s_dec[0][tid] + s_dec[1][tid] + p.decB1[0];
          if (s_row[tid] == s_col[tid]) v = 0.5f * sqrtf(p.edge_attr[gm]);
          p.dout[p.eid[gm]] = v;
        }
      }
      return;
    } else {
      // h = relu(acc + b0) -> LDS (XOR-swizzled); MODE1 aliases seg0, so
      // wait until ALL waves finished reading the A-tiles first.
      if constexpr (MODE == 1) __syncthreads();
      #pragma unroll
      for (int mt = 0; mt < 2; ++mt) {
        #pragma unroll
        for (int nt = 0; nt < 4; ++nt) {
          int colb = wn * 64 + nt * 16 + l15;
          float bb = p.b0[colb];
          #pragma unroll
          for (int r = 0; r < 4; ++r) {
            int rowb = wm * 32 + mt * 16 + l4 * 4 + r;
            float v = fmaxf(acc[mt][nt][r] + bb, 0.0f);
            a_lds[0][rowb * 128 + (colb ^ ((rowb & 7) << 3))] = f2bf(v);
          }
        }
      }
    }
  }

  if constexpr (MODE != 3) {
    __syncthreads();
    // layer1: out = h @ W1 + b1
    f32x4 acc1[2][4] = {};
    #pragma unroll
    for (int ks = 0; ks < 4; ++ks) {
      const int k = ks * 32 + l4 * 8;
      bf16x8 a1[2];
      #pragma unroll
      for (int mt = 0; mt < 2; ++mt) {
        int rowb = wm * 32 + mt * 16 + l15;
        a1[mt] = *(const bf16x8*)&a_lds[0][rowb * 128 + (k ^ ((rowb & 7) << 3))];
      }
      bf16x8 b1v[4];
      #pragma unroll
      for (int nt = 0; nt < 4; ++nt) {
        int n = wn * 64 + nt * 16 + l15;
        b1v[nt] = *(const bf16x8*)(p.Wt1 + (size_t)n * 128 + k);
      }
      #pragma unroll
      for (int mt = 0; mt < 2; ++mt)
        #pragma unroll
        for (int nt = 0; nt < 4; ++nt)
          acc1[mt][nt] = __builtin_amdgcn_mfma_f32_16x16x32_bf16(a1[mt], b1v[nt], acc1[mt][nt], 0, 0, 0);
    }
    #pragma unroll
    for (int mt = 0; mt < 2; ++mt) {
      #pragma unroll
      for (int nt = 0; nt < 4; ++nt) {
        int colb = wn * 64 + nt * 16 + l15;
        float bb = p.b1[colb];
        #pragma unroll
        for (int r = 0; r < 4; ++r) {
          int rowb = wm * 32 + mt * 16 + l4 * 4 + r;
          int gm = row0 + rowb;
          if (gm < M) {
            float v = acc1[mt][nt][r] + bb;
            p.outB[(size_t)gm * 128 + colb] = f2bf(v);
          }
        }
      }
    }
  }
}

struct TransDesc { const float* src[16]; unsigned short* dst[16]; int K[16]; };

__global__ void trans_kernel(TransDesc td) {
  int m = blockIdx.y;
  int k = blockIdx.x;
  if (k >= td.K[m]) return;
  int n = threadIdx.x;  // 128
  td.dst[m][(size_t)n * td.K[m] + k] = f2bf(td.src[m][(size_t)k * 128 + n]);
}

__global__ void deg_kernel(const int* __restrict__ row, int E, int* cnt) {
  int i = blockIdx.x * blockDim.x + threadIdx.x;
  if (i < E) atomicAdd(&cnt[row[i]], 1);
}

__global__ void invcnt_kernel(const int* __restrict__ cnt, int N, float* inv) {
  int i = blockIdx.x * blockDim.x + threadIdx.x;
  if (i < N) { int c = cnt[i]; inv[i] = 1.0f / (float)(c > 1 ? c : 1); }
}

// single-block exclusive scan of cnt[N] -> offs, cursor
__global__ __launch_bounds__(1024) void scan_kernel(const int* __restrict__ cnt, int N,
                                                    int* __restrict__ offs, int* __restrict__ cursor) {
  __shared__ int lds[1024];
  __shared__ int carry;
  if (threadIdx.x == 0) carry = 0;
  __syncthreads();
  for (int base = 0; base < N; base += 1024) {
    int i = base + (int)threadIdx.x;
    int v = (i < N) ? cnt[i] : 0;
    lds[threadIdx.x] = v;
    __syncthreads();
    #pragma unroll
    for (int off = 1; off < 1024; off <<= 1) {
      int t = (threadIdx.x >= (unsigned)off) ? lds[threadIdx.x - off] : 0;
      __syncthreads();
      lds[threadIdx.x] += t;
      __syncthreads();
    }
    int excl = lds[threadIdx.x] - v + carry;
    if (i < N) { offs[i] = excl; cursor[i] = excl; }
    __syncthreads();
    if (threadIdx.x == 1023) carry += lds[1023];
    __syncthreads();
  }
}

__global__ void scatter_kernel(const int* __restrict__ row, int E,
                               int* __restrict__ cursor, int* __restrict__ eid) {
  int i = blockIdx.x * blockDim.x + threadIdx.x;
  if (i < E) {
    int r = row[i];
    int pos = atomicAdd(&cursor[r], 1);
    eid[pos] = i;
  }
}

// build permuted row/col/edge_attr in CSR order
__global__ void permute_kernel(const int* __restrict__ eid,
                               const int* __restrict__ row, const int* __restrict__ col,
                               const float* __restrict__ ea, int E,
                               int* __restrict__ row_p, int* __restrict__ col_p,
                               float* __restrict__ ea_p) {
  int i = blockIdx.x * blockDim.x + threadIdx.x;
  if (i < E) {
    int e = eid[i];
    row_p[i] = row[e];
    col_p[i] = col[e];
    ea_p[i]  = ea[e];
  }
}

// CSR contiguous-range aggregation over permuted le: 4 nodes/block (1 wave each)
__global__ __launch_bounds__(256) void agg_kernel(const unsigned short* __restrict__ le,
                                                  const int* __restrict__ offs,
                                                  const int* __restrict__ cnt,
                                                  const float* __restrict__ inv,
                                                  unsigned short* __restrict__ aggb, int N) {
  int wave = threadIdx.x >> 6, lane = threadIdx.x & 63;
  int n = blockIdx.x * 4 + wave;
  if (n >= N) return;
  int beg = offs[n], d = cnt[n];
  const unsigned short* base = le + (size_t)beg * 128 + lane * 2;
  float sx0 = 0, sy0 = 0, sx1 = 0, sy1 = 0;
  int j = 0;
  for (; j + 1 < d; j += 2) {
    ushort2 v0 = *(const ushort2*)(base + (size_t)j * 128);
    ushort2 v1 = *(const ushort2*)(base + (size_t)(j + 1) * 128);
    sx0 += bf2f(v0.x); sy0 += bf2f(v0.y);
    sx1 += bf2f(v1.x); sy1 += bf2f(v1.y);
  }
  if (j < d) {
    ushort2 v0 = *(const ushort2*)(base + (size_t)j * 128);
    sx0 += bf2f(v0.x); sy0 += bf2f(v0.y);
  }
  float iv = inv[n];
  ushort2 o;
  o.x = f2bf((sx0 + sx1) * iv);
  o.y = f2bf((sy0 + sy1) * iv);
  *(ushort2*)(aggb + (size_t)n * 128 + lane * 2) = o;
}

extern "C" void kernel_launch(void* const* d_in, const int* in_sizes, int n_in,
                              void* d_out, int out_size, void* d_ws, size_t ws_size,
                              hipStream_t stream) {
  const float* x         = (const float*)d_in[0];
  const float* edge_attr = (const float*)d_in[1];
  const int*   eidx      = (const int*)  d_in[2];
  const float* encn_W0 = (const float*)d_in[3];
  const float* encn_b0 = (const float*)d_in[4];
  const float* encn_W1 = (const float*)d_in[5];
  const float* encn_b1 = (const float*)d_in[6];
  const float* ence_W0 = (const float*)d_in[7];
  const float* ence_b0 = (const float*)d_in[8];
  const float* ence_W1 = (const float*)d_in[9];
  const float* ence_b1 = (const float*)d_in[10];
  const float* dec_W0  = (const float*)d_in[11];
  const float* dec_b0  = (const float*)d_in[12];
  const float* dec_W1  = (const float*)d_in[13];
  const float* dec_b1  = (const float*)d_in[14];
  const float* eW0 = (const float*)d_in[15];
  const float* eb0 = (const float*)d_in[16];
  const float* eW1 = (const float*)d_in[17];
  const float* eb1 = (const float*)d_in[18];
  const float* nW0 = (const float*)d_in[19];
  const float* nb0 = (const float*)d_in[20];
  const float* nW1 = (const float*)d_in[21];
  const float* nb1 = (const float*)d_in[22];

  const int N = in_sizes[0];
  const int E = in_sizes[1];
  const int* rowI = eidx;
  const int* colI = eidx + E;

  char* w = (char*)d_ws;
  auto take = [&](size_t bytes) -> char* {
    char* p = w; w += (bytes + 255) & ~(size_t)255; return p;
  };
  unsigned short* ln   = (unsigned short*)take((size_t)N * 128 * 2);
  unsigned short* le   = (unsigned short*)take((size_t)E * 128 * 2);  // permuted (CSR) order
  unsigned short* aggb = (unsigned short*)take((size_t)N * 128 * 2);
  int*            cnt  = (int*)take((size_t)N * 4);
  float*          inv  = (float*)take((size_t)N * 4);
  int*            offs = (int*)take((size_t)N * 4);
  int*            curs = (int*)take((size_t)N * 4);
  int*            eidArr = (int*)take((size_t)E * 4);
  int*            row_p  = (int*)take((size_t)E * 4);
  int*            col_p  = (int*)take((size_t)E * 4);
  float*          ea_p   = (float*)take((size_t)E * 4);
  unsigned short* wt_encn1 = (unsigned short*)take(128 * 128 * 2);
  unsigned short* wt_ence1 = (unsigned short*)take(128 * 128 * 2);
  unsigned short* wt_dec0  = (unsigned short*)take(128 * 128 * 2);
  unsigned short *wt_e0[3], *wt_e1[3], *wt_n0[3], *wt_n1[3];
  for (int s = 0; s < 3; ++s) wt_e0[s] = (unsigned short*)take(384 * 128 * 2);
  for (int s = 0; s < 3; ++s) wt_e1[s] = (unsigned short*)take(128 * 128 * 2);
  for (int s = 0; s < 3; ++s) wt_n0[s] = (unsigned short*)take(256 * 128 * 2);
  for (int s = 0; s < 3; ++s) wt_n1[s] = (unsigned short*)take(128 * 128 * 2);

  TransDesc td{};
  int mi = 0;
  auto add = [&](const float* s, unsigned short* d, int K) {
    td.src[mi] = s; td.dst[mi] = d; td.K[mi] = K; ++mi;
  };
  add(encn_W1, wt_encn1, 128);
  add(ence_W1, wt_ence1, 128);
  add(dec_W0,  wt_dec0,  128);
  for (int s = 0; s < 3; ++s) add(eW0 + (size_t)s * 384 * 128, wt_e0[s], 384);
  for (int s = 0; s < 3; ++s) add(eW1 + (size_t)s * 128 * 128, wt_e1[s], 128);
  for (int s = 0; s < 3; ++s) add(nW0 + (size_t)s * 256 * 128, wt_n0[s], 256);
  for (int s = 0; s < 3; ++s) add(nW1 + (size_t)s * 128 * 128, wt_n1[s], 128);

  hipMemsetAsync(cnt, 0, (size_t)N * 4, stream);
  trans_kernel<<<dim3(384, mi), 128, 0, stream>>>(td);
  deg_kernel<<<(E + 255) / 256, 256, 0, stream>>>(rowI, E, cnt);
  invcnt_kernel<<<(N + 255) / 256, 256, 0, stream>>>(cnt, N, inv);
  scan_kernel<<<1, 1024, 0, stream>>>(cnt, N, offs, curs);
  scatter_kernel<<<(E + 255) / 256, 256, 0, stream>>>(rowI, E, curs, eidArr);
  permute_kernel<<<(E + 255) / 256, 256, 0, stream>>>(eidArr, rowI, colI, edge_attr, E,
                                                      row_p, col_p, ea_p);

  {
    MlpParams q{}; q.M = N; q.x = x; q.W0v = encn_W0; q.b0 = encn_b0;
    q.Wt1 = wt_encn1; q.b1 = encn_b1; q.outB = ln;
    mlp_kernel<0, 128><<<(N + 63) / 64, 256, 0, stream>>>(q);
  }
  {
    // edge encoder reads permuted edge_attr, writes permuted le
    MlpParams q{}; q.M = E; q.x = ea_p; q.W0v = ence_W0; q.b0 = ence_b0;
    q.Wt1 = wt_ence1; q.b1 = ence_b1; q.outB = le;
    mlp_kernel<0, 128><<<(E + 63) / 64, 256, 0, stream>>>(q);
  }

  for (int s = 0; s < 3; ++s) {
    {
      MlpParams q{}; q.M = E; q.ln = ln; q.src2 = le; q.rowIdx = row_p; q.colIdx = col_p;
      q.Wt0 = wt_e0[s]; q.b0 = eb0 + s * 128; q.Wt1 = wt_e1[s]; q.b1 = eb1 + s * 128;
      q.outB = le;
      mlp_kernel<1, 384><<<(E + 63) / 64, 256, 0, stream>>>(q);
    }
    agg_kernel<<<(N + 3) / 4, 256, 0, stream>>>(le, offs, cnt, inv, aggb, N);
    {
      MlpParams q{}; q.M = N; q.ln = ln; q.src2 = aggb;
      q.Wt0 = wt_n0[s]; q.b0 = nb0 + s * 128; q.Wt1 = wt_n1[s]; q.b1 = nb1 + s * 128;
      q.outB = ln;
      mlp_kernel<2, 256><<<(N + 63) / 64, 256, 0, stream>>>(q);
    }
  }
  {
    MlpParams q{}; q.M = E; q.ln = le; q.rowIdx = row_p; q.colIdx = col_p; q.eid = eidArr;
    q.Wt0 = wt_dec0; q.b0 = dec_b0; q.decW1 = dec_W1; q.decB1 = dec_b1;
    q.edge_attr = ea_p; q.dout = (float*)d_out;
    mlp_kernel<3, 128><<<(E + 63) / 64, 256, 0, stream>>>(q);
  }
}

// Round 5
// 832.505 us; speedup vs baseline: 1.2464x; 1.0777x over previous
//
#include <hip/hip_runtime.h>
#include <hip/hip_bf16.h>
#include <stdint.h>

typedef __attribute__((ext_vector_type(8))) short bf16x8;
typedef __attribute__((ext_vector_type(4))) float f32x4;

#define MFMA16(a, b, c) __builtin_amdgcn_mfma_f32_16x16x32_bf16((a), (b), (c), 0, 0, 0)

static __device__ __forceinline__ unsigned short f2bf(float f) {
  union { float f; uint32_t u; } c; c.f = f;
  uint32_t r = (c.u + 0x7FFFu + ((c.u >> 16) & 1u)) >> 16;
  return (unsigned short)r;
}
static __device__ __forceinline__ float bf2f(unsigned short u) {
  union { uint32_t u; float f; } c; c.u = (uint32_t)u << 16; return c.f;
}
static __device__ __forceinline__ void gload_lds16(const void* g, void* l) {
  __builtin_amdgcn_global_load_lds((const __attribute__((address_space(1))) void*)g,
                                   (__attribute__((address_space(3))) void*)l, 16, 0, 0);
}

// ---------------- encoder: rank-1 layer0 + GEMM layer1 (B1 in regs) ----------------
__global__ __launch_bounds__(256) void enc_kernel(
    int M, const float* __restrict__ x, const float* __restrict__ W0v,
    const float* __restrict__ b0, const unsigned short* __restrict__ wt1,
    const float* __restrict__ b1, unsigned short* __restrict__ outB) {
  __shared__ __align__(16) unsigned short h_lds[64 * 128];
  const int tid = threadIdx.x, wave = tid >> 6, lane = tid & 63;
  const int wm = wave >> 1, wn = wave & 1, l15 = lane & 15, l4 = lane >> 4;
  const int row0 = blockIdx.x * 64;

  bf16x8 b1f[4][4];
  #pragma unroll
  for (int nt = 0; nt < 4; ++nt) {
    int n = wn * 64 + nt * 16 + l15;
    #pragma unroll
    for (int ks = 0; ks < 4; ++ks)
      b1f[ks][nt] = *(const bf16x8*)(wt1 + (size_t)n * 128 + ks * 32 + l4 * 8);
  }
  #pragma unroll
  for (int mt = 0; mt < 2; ++mt)
    #pragma unroll
    for (int r = 0; r < 4; ++r) {
      int rowb = wm * 32 + mt * 16 + l4 * 4 + r;
      int gm = row0 + rowb; if (gm > M - 1) gm = M - 1;
      float xv = x[gm];
      #pragma unroll
      for (int nt = 0; nt < 4; ++nt) {
        int colb = wn * 64 + nt * 16 + l15;
        float v = fmaxf(xv * W0v[colb] + b0[colb], 0.0f);
        h_lds[rowb * 128 + (colb ^ ((rowb & 7) << 3))] = f2bf(v);
      }
    }
  __syncthreads();
  f32x4 acc[2][4] = {};
  #pragma unroll
  for (int ks = 0; ks < 4; ++ks) {
    bf16x8 a1[2];
    #pragma unroll
    for (int mt = 0; mt < 2; ++mt) {
      int rowb = wm * 32 + mt * 16 + l15;
      a1[mt] = *(const bf16x8*)&h_lds[rowb * 128 + ((ks * 32 + l4 * 8) ^ ((rowb & 7) << 3))];
    }
    #pragma unroll
    for (int mt = 0; mt < 2; ++mt)
      #pragma unroll
      for (int nt = 0; nt < 4; ++nt)
        acc[mt][nt] = MFMA16(a1[mt], b1f[ks][nt], acc[mt][nt]);
  }
  #pragma unroll
  for (int mt = 0; mt < 2; ++mt)
    #pragma unroll
    for (int nt = 0; nt < 4; ++nt) {
      int colb = wn * 64 + nt * 16 + l15;
      float bb = b1[colb];
      #pragma unroll
      for (int r = 0; r < 4; ++r) {
        int rowb = wm * 32 + mt * 16 + l4 * 4 + r;
        int gm = row0 + rowb;
        if (gm < M) outB[(size_t)gm * 128 + colb] = f2bf(acc[mt][nt][r] + bb);
      }
    }
}

// ---------------- Pr = ln @ W0r^T, Pc = ln @ W0c^T (dual-output GEMM) ----------------
__global__ __launch_bounds__(256) void pgemm_kernel(
    int M, const unsigned short* __restrict__ ln,
    const unsigned short* __restrict__ wt,  // [128][384]
    unsigned short* __restrict__ pr, unsigned short* __restrict__ pc) {
  const int tid = threadIdx.x, wave = tid >> 6, lane = tid & 63;
  const int wm = wave >> 1, wn = wave & 1, l15 = lane & 15, l4 = lane >> 4;
  const int row0 = blockIdx.x * 64;

  bf16x8 a[2][4];
  #pragma unroll
  for (int mt = 0; mt < 2; ++mt) {
    int gm = row0 + wm * 32 + mt * 16 + l15; if (gm > M - 1) gm = M - 1;
    #pragma unroll
    for (int ks = 0; ks < 4; ++ks)
      a[mt][ks] = *(const bf16x8*)(ln + (size_t)gm * 128 + ks * 32 + l4 * 8);
  }
  bf16x8 bR[4][4], bC[4][4];
  #pragma unroll
  for (int nt = 0; nt < 4; ++nt) {
    int n = wn * 64 + nt * 16 + l15;
    #pragma unroll
    for (int ks = 0; ks < 4; ++ks) {
      int k = ks * 32 + l4 * 8;
      bR[ks][nt] = *(const bf16x8*)(wt + (size_t)n * 384 + k);
      bC[ks][nt] = *(const bf16x8*)(wt + (size_t)n * 384 + 128 + k);
    }
  }
  f32x4 accR[2][4] = {}, accC[2][4] = {};
  #pragma unroll
  for (int ks = 0; ks < 4; ++ks)
    #pragma unroll
    for (int mt = 0; mt < 2; ++mt)
      #pragma unroll
      for (int nt = 0; nt < 4; ++nt) {
        accR[mt][nt] = MFMA16(a[mt][ks], bR[ks][nt], accR[mt][nt]);
        accC[mt][nt] = MFMA16(a[mt][ks], bC[ks][nt], accC[mt][nt]);
      }
  #pragma unroll
  for (int mt = 0; mt < 2; ++mt)
    #pragma unroll
    for (int nt = 0; nt < 4; ++nt) {
      int colb = wn * 64 + nt * 16 + l15;
      #pragma unroll
      for (int r = 0; r < 4; ++r) {
        int rowb = wm * 32 + mt * 16 + l4 * 4 + r;
        int gm = row0 + rowb;
        if (gm < M) {
          pr[(size_t)gm * 128 + colb] = f2bf(accR[mt][nt][r]);
          pc[(size_t)gm * 128 + colb] = f2bf(accC[mt][nt][r]);
        }
      }
    }
}

// ---------------- edge block: le-GEMM + gathered Pr/Pc adds + layer1 ----------------
__global__ __launch_bounds__(256) void edge_kernel(
    int E, unsigned short* __restrict__ le,  // in/out (own rows only)
    const unsigned short* __restrict__ pr, const unsigned short* __restrict__ pc,
    const int* __restrict__ row_p, const int* __restrict__ col_p,
    const unsigned short* __restrict__ wt0,  // [128][384], W0e slice at k-offset 256
    const float* __restrict__ b0,
    const unsigned short* __restrict__ wt1,  // [128][128]
    const float* __restrict__ b1) {
  __shared__ __align__(16) unsigned short pr_lds[64 * 128];  // reused as h-tile
  __shared__ __align__(16) unsigned short pc_lds[64 * 128];
  __shared__ int s_row[64], s_col[64];
  const int tid = threadIdx.x, wave = tid >> 6, lane = tid & 63;
  const int wm = wave >> 1, wn = wave & 1, l15 = lane & 15, l4 = lane >> 4;
  const int row0 = blockIdx.x * 64;

  if (tid < 64) {
    int e = row0 + tid; if (e > E - 1) e = E - 1;
    s_row[tid] = row_p[e];
    s_col[tid] = col_p[e];
  }
  __syncthreads();

  // issue Pr/Pc row gathers (linear LDS dest: wave-uniform base + lane*16)
  const int jj = lane & 15;
  #pragma unroll
  for (int i = 0; i < 4; ++i) {
    int rowl = 16 * wave + 4 * i + (lane >> 4);
    gload_lds16(pr + (size_t)s_row[rowl] * 128 + jj * 8, &pr_lds[(16 * wave + 4 * i) * 128]);
    gload_lds16(pc + (size_t)s_col[rowl] * 128 + jj * 8, &pc_lds[(16 * wave + 4 * i) * 128]);
  }

  // A = le rows (contiguous), all frags loaded up-front
  bf16x8 a[2][4];
  #pragma unroll
  for (int mt = 0; mt < 2; ++mt) {
    int gm = row0 + wm * 32 + mt * 16 + l15; if (gm > E - 1) gm = E - 1;
    #pragma unroll
    for (int ks = 0; ks < 4; ++ks)
      a[mt][ks] = *(const bf16x8*)(le + (size_t)gm * 128 + ks * 32 + l4 * 8);
  }
  // B0 = W0e slice, preloaded to regs
  bf16x8 b0f[4][4];
  #pragma unroll
  for (int nt = 0; nt < 4; ++nt) {
    int n = wn * 64 + nt * 16 + l15;
    #pragma unroll
    for (int ks = 0; ks < 4; ++ks)
      b0f[ks][nt] = *(const bf16x8*)(wt0 + (size_t)n * 384 + 256 + ks * 32 + l4 * 8);
  }
  f32x4 acc[2][4] = {};
  #pragma unroll
  for (int ks = 0; ks < 4; ++ks)
    #pragma unroll
    for (int mt = 0; mt < 2; ++mt)
      #pragma unroll
      for (int nt = 0; nt < 4; ++nt)
        acc[mt][nt] = MFMA16(a[mt][ks], b0f[ks][nt], acc[mt][nt]);

  // B1 preload (in flight across the barrier/epilogue)
  bf16x8 b1f[4][4];
  #pragma unroll
  for (int nt = 0; nt < 4; ++nt) {
    int n = wn * 64 + nt * 16 + l15;
    #pragma unroll
    for (int ks = 0; ks < 4; ++ks)
      b1f[ks][nt] = *(const bf16x8*)(wt1 + (size_t)n * 128 + ks * 32 + l4 * 8);
  }

  __syncthreads();  // gathers drained (vmcnt) + all waves ready

  // h = relu(acc + Pr[row] + Pc[col] + b0)
  float hv[2][4][4];
  #pragma unroll
  for (int mt = 0; mt < 2; ++mt)
    #pragma unroll
    for (int nt = 0; nt < 4; ++nt) {
      int colb = wn * 64 + nt * 16 + l15;
      float bb = b0[colb];
      #pragma unroll
      for (int r = 0; r < 4; ++r) {
        int rowb = wm * 32 + mt * 16 + l4 * 4 + r;
        float addv = bf2f(pr_lds[rowb * 128 + colb]) + bf2f(pc_lds[rowb * 128 + colb]);
        hv[mt][nt][r] = fmaxf(acc[mt][nt][r] + addv + bb, 0.0f);
      }
    }
  __syncthreads();  // all Pr reads done before overwriting pr_lds with h
  #pragma unroll
  for (int mt = 0; mt < 2; ++mt)
    #pragma unroll
    for (int nt = 0; nt < 4; ++nt) {
      int colb = wn * 64 + nt * 16 + l15;
      #pragma unroll
      for (int r = 0; r < 4; ++r) {
        int rowb = wm * 32 + mt * 16 + l4 * 4 + r;
        pr_lds[rowb * 128 + (colb ^ ((rowb & 7) << 3))] = f2bf(hv[mt][nt][r]);
      }
    }
  __syncthreads();

  // layer1
  f32x4 acc1[2][4] = {};
  #pragma unroll
  for (int ks = 0; ks < 4; ++ks) {
    bf16x8 a1[2];
    #pragma unroll
    for (int mt = 0; mt < 2; ++mt) {
      int rowb = wm * 32 + mt * 16 + l15;
      a1[mt] = *(const bf16x8*)&pr_lds[rowb * 128 + ((ks * 32 + l4 * 8) ^ ((rowb & 7) << 3))];
    }
    #pragma unroll
    for (int mt = 0; mt < 2; ++mt)
      #pragma unroll
      for (int nt = 0; nt < 4; ++nt)
        acc1[mt][nt] = MFMA16(a1[mt], b1f[ks][nt], acc1[mt][nt]);
  }
  #pragma unroll
  for (int mt = 0; mt < 2; ++mt)
    #pragma unroll
    for (int nt = 0; nt < 4; ++nt) {
      int colb = wn * 64 + nt * 16 + l15;
      float bb = b1[colb];
      #pragma unroll
      for (int r = 0; r < 4; ++r) {
        int rowb = wm * 32 + mt * 16 + l4 * 4 + r;
        int gm = row0 + rowb;
        if (gm < E) le[(size_t)gm * 128 + colb] = f2bf(acc1[mt][nt][r] + bb);
      }
    }
}

// ---------------- node block: K=256 contiguous concat, B in regs ----------------
__global__ __launch_bounds__(256) void node_kernel(
    int M, unsigned short* __restrict__ ln, const unsigned short* __restrict__ aggb,
    const unsigned short* __restrict__ wt0,  // [128][256]
    const float* __restrict__ b0,
    const unsigned short* __restrict__ wt1, const float* __restrict__ b1) {
  __shared__ __align__(16) unsigned short h_lds[64 * 128];
  const int tid = threadIdx.x, wave = tid >> 6, lane = tid & 63;
  const int wm = wave >> 1, wn = wave & 1, l15 = lane & 15, l4 = lane >> 4;
  const int row0 = blockIdx.x * 64;

  bf16x8 a[2][8];
  #pragma unroll
  for (int mt = 0; mt < 2; ++mt) {
    int gm = row0 + wm * 32 + mt * 16 + l15; if (gm > M - 1) gm = M - 1;
    #pragma unroll
    for (int ks = 0; ks < 4; ++ks) {
      a[mt][ks]     = *(const bf16x8*)(ln   + (size_t)gm * 128 + ks * 32 + l4 * 8);
      a[mt][4 + ks] = *(const bf16x8*)(aggb + (size_t)gm * 128 + ks * 32 + l4 * 8);
    }
  }
  bf16x8 b0f[8][4];
  #pragma unroll
  for (int nt = 0; nt < 4; ++nt) {
    int n = wn * 64 + nt * 16 + l15;
    #pragma unroll
    for (int ks = 0; ks < 8; ++ks)
      b0f[ks][nt] = *(const bf16x8*)(wt0 + (size_t)n * 256 + ks * 32 + l4 * 8);
  }
  f32x4 acc[2][4] = {};
  #pragma unroll
  for (int ks = 0; ks < 8; ++ks)
    #pragma unroll
    for (int mt = 0; mt < 2; ++mt)
      #pragma unroll
      for (int nt = 0; nt < 4; ++nt)
        acc[mt][nt] = MFMA16(a[mt][ks], b0f[ks][nt], acc[mt][nt]);

  bf16x8 b1f[4][4];
  #pragma unroll
  for (int nt = 0; nt < 4; ++nt) {
    int n = wn * 64 + nt * 16 + l15;
    #pragma unroll
    for (int ks = 0; ks < 4; ++ks)
      b1f[ks][nt] = *(const bf16x8*)(wt1 + (size_t)n * 128 + ks * 32 + l4 * 8);
  }
  #pragma unroll
  for (int mt = 0; mt < 2; ++mt)
    #pragma unroll
    for (int nt = 0; nt < 4; ++nt) {
      int colb = wn * 64 + nt * 16 + l15;
      float bb = b0[colb];
      #pragma unroll
      for (int r = 0; r < 4; ++r) {
        int rowb = wm * 32 + mt * 16 + l4 * 4 + r;
        h_lds[rowb * 128 + (colb ^ ((rowb & 7) << 3))] = f2bf(fmaxf(acc[mt][nt][r] + bb, 0.0f));
      }
    }
  __syncthreads();
  f32x4 acc1[2][4] = {};
  #pragma unroll
  for (int ks = 0; ks < 4; ++ks) {
    bf16x8 a1[2];
    #pragma unroll
    for (int mt = 0; mt < 2; ++mt) {
      int rowb = wm * 32 + mt * 16 + l15;
      a1[mt] = *(const bf16x8*)&h_lds[rowb * 128 + ((ks * 32 + l4 * 8) ^ ((rowb & 7) << 3))];
    }
    #pragma unroll
    for (int mt = 0; mt < 2; ++mt)
      #pragma unroll
      for (int nt = 0; nt < 4; ++nt)
        acc1[mt][nt] = MFMA16(a1[mt], b1f[ks][nt], acc1[mt][nt]);
  }
  #pragma unroll
  for (int mt = 0; mt < 2; ++mt)
    #pragma unroll
    for (int nt = 0; nt < 4; ++nt) {
      int colb = wn * 64 + nt * 16 + l15;
      float bb = b1[colb];
      #pragma unroll
      for (int r = 0; r < 4; ++r) {
        int rowb = wm * 32 + mt * 16 + l4 * 4 + r;
        int gm = row0 + rowb;
        if (gm < M) ln[(size_t)gm * 128 + colb] = f2bf(acc1[mt][nt][r] + bb);
      }
    }
}

// ---------------- decoder: le-GEMM + dot-reduce + diag overwrite + scatter ----------------
__global__ __launch_bounds__(256) void dec_kernel(
    int E, const unsigned short* __restrict__ le,
    const int* __restrict__ row_p, const int* __restrict__ col_p,
    const int* __restrict__ eid, const float* __restrict__ ea_p,
    const unsigned short* __restrict__ wt0, const float* __restrict__ b0,
    const float* __restrict__ decW1, const float* __restrict__ decB1,
    float* __restrict__ dout) {
  __shared__ float s_dec[2][64];
  __shared__ int s_row[64], s_col[64];
  const int tid = threadIdx.x, wave = tid >> 6, lane = tid & 63;
  const int wm = wave >> 1, wn = wave & 1, l15 = lane & 15, l4 = lane >> 4;
  const int row0 = blockIdx.x * 64;

  if (tid < 64) {
    int e = row0 + tid; if (e > E - 1) e = E - 1;
    s_row[tid] = row_p[e];
    s_col[tid] = col_p[e];
  }
  bf16x8 a[2][4];
  #pragma unroll
  for (int mt = 0; mt < 2; ++mt) {
    int gm = row0 + wm * 32 + mt * 16 + l15; if (gm > E - 1) gm = E - 1;
    #pragma unroll
    for (int ks = 0; ks < 4; ++ks)
      a[mt][ks] = *(const bf16x8*)(le + (size_t)gm * 128 + ks * 32 + l4 * 8);
  }
  bf16x8 b0f[4][4];
  #pragma unroll
  for (int nt = 0; nt < 4; ++nt) {
    int n = wn * 64 + nt * 16 + l15;
    #pragma unroll
    for (int ks = 0; ks < 4; ++ks)
      b0f[ks][nt] = *(const bf16x8*)(wt0 + (size_t)n * 128 + ks * 32 + l4 * 8);
  }
  f32x4 acc[2][4] = {};
  #pragma unroll
  for (int ks = 0; ks < 4; ++ks)
    #pragma unroll
    for (int mt = 0; mt < 2; ++mt)
      #pragma unroll
      for (int nt = 0; nt < 4; ++nt)
        acc[mt][nt] = MFMA16(a[mt][ks], b0f[ks][nt], acc[mt][nt]);

  float part[2][4] = {};
  #pragma unroll
  for (int mt = 0; mt < 2; ++mt)
    #pragma unroll
    for (int nt = 0; nt < 4; ++nt) {
      int colb = wn * 64 + nt * 16 + l15;
      float w1 = decW1[colb];
      float bb = b0[colb];
      #pragma unroll
      for (int r = 0; r < 4; ++r)
        part[mt][r] += fmaxf(acc[mt][nt][r] + bb, 0.0f) * w1;
    }
  #pragma unroll
  for (int mt = 0; mt < 2; ++mt)
    #pragma unroll
    for (int r = 0; r < 4; ++r) {
      float v = part[mt][r];
      #pragma unroll
      for (int off = 1; off < 16; off <<= 1) v += __shfl_xor(v, off, 64);
      if (l15 == 0) s_dec[wn][wm * 32 + mt * 16 + l4 * 4 + r] = v;
    }
  __syncthreads();
  if (tid < 64) {
    int gm = row0 + tid;
    if (gm < E) {
      float v = s_dec[0][tid] + s_dec[1][tid] + decB1[0];
      if (s_row[tid] == s_col[tid]) v = 0.5f * sqrtf(ea_p[gm]);
      dout[eid[gm]] = v;
    }
  }
}

// ---------------- graph prep ----------------
struct TransDesc { const float* src[16]; unsigned short* dst[16]; int K[16]; };

__global__ void trans_kernel(TransDesc td) {
  int m = blockIdx.y;
  int k = blockIdx.x;
  if (k >= td.K[m]) return;
  int n = threadIdx.x;  // 128
  td.dst[m][(size_t)n * td.K[m] + k] = f2bf(td.src[m][(size_t)k * 128 + n]);
}

__global__ void deg_kernel(const int* __restrict__ row, int E, int* cnt) {
  int i = blockIdx.x * blockDim.x + threadIdx.x;
  if (i < E) atomicAdd(&cnt[row[i]], 1);
}

__global__ void invcnt_kernel(const int* __restrict__ cnt, int N, float* inv) {
  int i = blockIdx.x * blockDim.x + threadIdx.x;
  if (i < N) { int c = cnt[i]; inv[i] = 1.0f / (float)(c > 1 ? c : 1); }
}

__global__ __launch_bounds__(1024) void scan_kernel(const int* __restrict__ cnt, int N,
                                                    int* __restrict__ offs, int* __restrict__ cursor) {
  __shared__ int lds[1024];
  __shared__ int carry;
  if (threadIdx.x == 0) carry = 0;
  __syncthreads();
  for (int base = 0; base < N; base += 1024) {
    int i = base + (int)threadIdx.x;
    int v = (i < N) ? cnt[i] : 0;
    lds[threadIdx.x] = v;
    __syncthreads();
    #pragma unroll
    for (int off = 1; off < 1024; off <<= 1) {
      int t = (threadIdx.x >= (unsigned)off) ? lds[threadIdx.x - off] : 0;
      __syncthreads();
      lds[threadIdx.x] += t;
      __syncthreads();
    }
    int excl = lds[threadIdx.x] - v + carry;
    if (i < N) { offs[i] = excl; cursor[i] = excl; }
    __syncthreads();
    if (threadIdx.x == 1023) carry += lds[1023];
    __syncthreads();
  }
}

__global__ void scatter_kernel(const int* __restrict__ row, int E,
                               int* __restrict__ cursor, int* __restrict__ eid) {
  int i = blockIdx.x * blockDim.x + threadIdx.x;
  if (i < E) {
    int r = row[i];
    int pos = atomicAdd(&cursor[r], 1);
    eid[pos] = i;
  }
}

__global__ void permute_kernel(const int* __restrict__ eid,
                               const int* __restrict__ row, const int* __restrict__ col,
                               const float* __restrict__ ea, int E,
                               int* __restrict__ row_p, int* __restrict__ col_p,
                               float* __restrict__ ea_p) {
  int i = blockIdx.x * blockDim.x + threadIdx.x;
  if (i < E) {
    int e = eid[i];
    row_p[i] = row[e];
    col_p[i] = col[e];
    ea_p[i]  = ea[e];
  }
}

// CSR contiguous aggregation over permuted le
__global__ __launch_bounds__(256) void agg_kernel(const unsigned short* __restrict__ le,
                                                  const int* __restrict__ offs,
                                                  const int* __restrict__ cnt,
                                                  const float* __restrict__ inv,
                                                  unsigned short* __restrict__ aggb, int N) {
  int wave = threadIdx.x >> 6, lane = threadIdx.x & 63;
  int n = blockIdx.x * 4 + wave;
  if (n >= N) return;
  int beg = offs[n], d = cnt[n];
  const unsigned short* base = le + (size_t)beg * 128 + lane * 2;
  float sx0 = 0, sy0 = 0, sx1 = 0, sy1 = 0, sx2 = 0, sy2 = 0, sx3 = 0, sy3 = 0;
  int j = 0;
  for (; j + 3 < d; j += 4) {
    ushort2 v0 = *(const ushort2*)(base + (size_t)j * 128);
    ushort2 v1 = *(const ushort2*)(base + (size_t)(j + 1) * 128);
    ushort2 v2 = *(const ushort2*)(base + (size_t)(j + 2) * 128);
    ushort2 v3 = *(const ushort2*)(base + (size_t)(j + 3) * 128);
    sx0 += bf2f(v0.x); sy0 += bf2f(v0.y);
    sx1 += bf2f(v1.x); sy1 += bf2f(v1.y);
    sx2 += bf2f(v2.x); sy2 += bf2f(v2.y);
    sx3 += bf2f(v3.x); sy3 += bf2f(v3.y);
  }
  for (; j < d; ++j) {
    ushort2 v0 = *(const ushort2*)(base + (size_t)j * 128);
    sx0 += bf2f(v0.x); sy0 += bf2f(v0.y);
  }
  float iv = inv[n];
  ushort2 o;
  o.x = f2bf((sx0 + sx1 + sx2 + sx3) * iv);
  o.y = f2bf((sy0 + sy1 + sy2 + sy3) * iv);
  *(ushort2*)(aggb + (size_t)n * 128 + lane * 2) = o;
}

extern "C" void kernel_launch(void* const* d_in, const int* in_sizes, int n_in,
                              void* d_out, int out_size, void* d_ws, size_t ws_size,
                              hipStream_t stream) {
  const float* x         = (const float*)d_in[0];
  const float* edge_attr = (const float*)d_in[1];
  const int*   eidx      = (const int*)  d_in[2];
  const float* encn_W0 = (const float*)d_in[3];
  const float* encn_b0 = (const float*)d_in[4];
  const float* encn_W1 = (const float*)d_in[5];
  const float* encn_b1 = (const float*)d_in[6];
  const float* ence_W0 = (const float*)d_in[7];
  const float* ence_b0 = (const float*)d_in[8];
  const float* ence_W1 = (const float*)d_in[9];
  const float* ence_b1 = (const float*)d_in[10];
  const float* dec_W0  = (const float*)d_in[11];
  const float* dec_b0  = (const float*)d_in[12];
  const float* dec_W1  = (const float*)d_in[13];
  const float* dec_b1  = (const float*)d_in[14];
  const float* eW0 = (const float*)d_in[15];
  const float* eb0 = (const float*)d_in[16];
  const float* eW1 = (const float*)d_in[17];
  const float* eb1 = (const float*)d_in[18];
  const float* nW0 = (const float*)d_in[19];
  const float* nb0 = (const float*)d_in[20];
  const float* nW1 = (const float*)d_in[21];
  const float* nb1 = (const float*)d_in[22];

  const int N = in_sizes[0];
  const int E = in_sizes[1];
  const int* rowI = eidx;
  const int* colI = eidx + E;

  char* w = (char*)d_ws;
  auto take = [&](size_t bytes) -> char* {
    char* p = w; w += (bytes + 255) & ~(size_t)255; return p;
  };
  unsigned short* ln   = (unsigned short*)take((size_t)N * 128 * 2);
  unsigned short* le   = (unsigned short*)take((size_t)E * 128 * 2);  // CSR order
  unsigned short* aggb = (unsigned short*)take((size_t)N * 128 * 2);
  unsigned short* pr   = (unsigned short*)take((size_t)N * 128 * 2);
  unsigned short* pc   = (unsigned short*)take((size_t)N * 128 * 2);
  int*            cnt  = (int*)take((size_t)N * 4);
  float*          inv  = (float*)take((size_t)N * 4);
  int*            offs = (int*)take((size_t)N * 4);
  int*            curs = (int*)take((size_t)N * 4);
  int*            eidArr = (int*)take((size_t)E * 4);
  int*            row_p  = (int*)take((size_t)E * 4);
  int*            col_p  = (int*)take((size_t)E * 4);
  float*          ea_p   = (float*)take((size_t)E * 4);
  unsigned short* wt_encn1 = (unsigned short*)take(128 * 128 * 2);
  unsigned short* wt_ence1 = (unsigned short*)take(128 * 128 * 2);
  unsigned short* wt_dec0  = (unsigned short*)take(128 * 128 * 2);
  unsigned short *wt_e0[3], *wt_e1[3], *wt_n0[3], *wt_n1[3];
  for (int s = 0; s < 3; ++s) wt_e0[s] = (unsigned short*)take(384 * 128 * 2);
  for (int s = 0; s < 3; ++s) wt_e1[s] = (unsigned short*)take(128 * 128 * 2);
  for (int s = 0; s < 3; ++s) wt_n0[s] = (unsigned short*)take(256 * 128 * 2);
  for (int s = 0; s < 3; ++s) wt_n1[s] = (unsigned short*)take(128 * 128 * 2);

  TransDesc td{};
  int mi = 0;
  auto add = [&](const float* s, unsigned short* d, int K) {
    td.src[mi] = s; td.dst[mi] = d; td.K[mi] = K; ++mi;
  };
  add(encn_W1, wt_encn1, 128);
  add(ence_W1, wt_ence1, 128);
  add(dec_W0,  wt_dec0,  128);
  for (int s = 0; s < 3; ++s) add(eW0 + (size_t)s * 384 * 128, wt_e0[s], 384);
  for (int s = 0; s < 3; ++s) add(eW1 + (size_t)s * 128 * 128, wt_e1[s], 128);
  for (int s = 0; s < 3; ++s) add(nW0 + (size_t)s * 256 * 128, wt_n0[s], 256);
  for (int s = 0; s < 3; ++s) add(nW1 + (size_t)s * 128 * 128, wt_n1[s], 128);

  hipMemsetAsync(cnt, 0, (size_t)N * 4, stream);
  trans_kernel<<<dim3(384, mi), 128, 0, stream>>>(td);
  deg_kernel<<<(E + 255) / 256, 256, 0, stream>>>(rowI, E, cnt);
  invcnt_kernel<<<(N + 255) / 256, 256, 0, stream>>>(cnt, N, inv);
  scan_kernel<<<1, 1024, 0, stream>>>(cnt, N, offs, curs);
  scatter_kernel<<<(E + 255) / 256, 256, 0, stream>>>(rowI, E, curs, eidArr);
  permute_kernel<<<(E + 255) / 256, 256, 0, stream>>>(eidArr, rowI, colI, edge_attr, E,
                                                      row_p, col_p, ea_p);

  enc_kernel<<<(N + 63) / 64, 256, 0, stream>>>(N, x, encn_W0, encn_b0, wt_encn1, encn_b1, ln);
  enc_kernel<<<(E + 63) / 64, 256, 0, stream>>>(E, ea_p, ence_W0, ence_b0, wt_ence1, ence_b1, le);

  for (int s = 0; s < 3; ++s) {
    pgemm_kernel<<<(N + 63) / 64, 256, 0, stream>>>(N, ln, wt_e0[s], pr, pc);
    edge_kernel<<<(E + 63) / 64, 256, 0, stream>>>(E, le, pr, pc, row_p, col_p,
                                                   wt_e0[s], eb0 + s * 128,
                                                   wt_e1[s], eb1 + s * 128);
    agg_kernel<<<(N + 3) / 4, 256, 0, stream>>>(le, offs, cnt, inv, aggb, N);
    node_kernel<<<(N + 63) / 64, 256, 0, stream>>>(N, ln, aggb, wt_n0[s], nb0 + s * 128,
                                                   wt_n1[s], nb1 + s * 128);
  }
  dec_kernel<<<(E + 63) / 64, 256, 0, stream>>>(E, le, row_p, col_p, eidArr, ea_p,
                                                wt_dec0, dec_b0, dec_W1, dec_b1,
                                                (float*)d_out);
}

// Round 6
// 582.983 us; speedup vs baseline: 1.7799x; 1.4280x over previous
//
#include <hip/hip_runtime.h>
#include <hip/hip_bf16.h>
#include <stdint.h>

typedef __attribute__((ext_vector_type(8))) short bf16x8;
typedef __attribute__((ext_vector_type(4))) float f32x4;

#define MFMA16(a, b, c) __builtin_amdgcn_mfma_f32_16x16x32_bf16((a), (b), (c), 0, 0, 0)

// raw barrier: drain own LDS ops, then s_barrier. NO vmcnt drain -> global
// prefetch loads stay in flight across the barrier.
#define BARRIER_LGKM() do { \
  asm volatile("s_waitcnt lgkmcnt(0)" ::: "memory"); \
  __builtin_amdgcn_sched_barrier(0); \
  __builtin_amdgcn_s_barrier(); \
  __builtin_amdgcn_sched_barrier(0); } while (0)

static __device__ __forceinline__ unsigned short f2bf(float f) {
  union { float f; uint32_t u; } c; c.f = f;
  uint32_t r = (c.u + 0x7FFFu + ((c.u >> 16) & 1u)) >> 16;
  return (unsigned short)r;
}
static __device__ __forceinline__ float bf2f(unsigned short u) {
  union { uint32_t u; float f; } c; c.u = (uint32_t)u << 16; return c.f;
}

// ---------------- persistent pipelined encoder (rank-1 layer0 + GEMM layer1) ----------------
__global__ __launch_bounds__(256) void enc_kernel(
    int M, int tiles, int tpb, const float* __restrict__ x,
    const float* __restrict__ W0v, const float* __restrict__ b0,
    const unsigned short* __restrict__ wt1, const float* __restrict__ b1,
    unsigned short* __restrict__ outB) {
  __shared__ __align__(16) unsigned short h_lds[64 * 128];
  __shared__ float s_x[64];
  const int tid = threadIdx.x, wave = tid >> 6, lane = tid & 63;
  const int wm = wave >> 1, wn = wave & 1, l15 = lane & 15, l4 = lane >> 4;
  int t0 = blockIdx.x * tpb, t1 = t0 + tpb; if (t1 > tiles) t1 = tiles;
  if (t0 >= tiles) return;

  bf16x8 b1f[4][4];
  float w0c[4], b0c[4], bb1[4];
  #pragma unroll
  for (int nt = 0; nt < 4; ++nt) {
    int n = wn * 64 + nt * 16 + l15;
    w0c[nt] = W0v[n]; b0c[nt] = b0[n]; bb1[nt] = b1[n];
    #pragma unroll
    for (int ks = 0; ks < 4; ++ks)
      b1f[ks][nt] = *(const bf16x8*)(wt1 + (size_t)n * 128 + ks * 32 + l4 * 8);
  }

  int row0 = t0 * 64;
  int xi = row0 + (tid & 63); if (xi > M - 1) xi = M - 1;
  float xr = x[xi];

  for (int t = t0; t < t1; ++t) {
    int nt_ = (t + 1 < t1) ? (t + 1) : t;
    int nrow0 = nt_ * 64;
    if (wave == 0) s_x[lane] = xr;
    BARRIER_LGKM();
    #pragma unroll
    for (int mt = 0; mt < 2; ++mt)
      #pragma unroll
      for (int r = 0; r < 4; ++r) {
        int rowb = wm * 32 + mt * 16 + l4 * 4 + r;
        float xv = s_x[rowb];
        #pragma unroll
        for (int nt = 0; nt < 4; ++nt) {
          int colb = wn * 64 + nt * 16 + l15;
          float v = fmaxf(xv * w0c[nt] + b0c[nt], 0.0f);
          h_lds[rowb * 128 + (colb ^ ((rowb & 7) << 3))] = f2bf(v);
        }
      }
    // prefetch next x
    int nxi = nrow0 + (tid & 63); if (nxi > M - 1) nxi = M - 1;
    xr = x[nxi];
    BARRIER_LGKM();
    f32x4 acc[2][4] = {};
    #pragma unroll
    for (int ks = 0; ks < 4; ++ks) {
      bf16x8 a1[2];
      #pragma unroll
      for (int mt = 0; mt < 2; ++mt) {
        int rowb = wm * 32 + mt * 16 + l15;
        a1[mt] = *(const bf16x8*)&h_lds[rowb * 128 + ((ks * 32 + l4 * 8) ^ ((rowb & 7) << 3))];
      }
      #pragma unroll
      for (int mt = 0; mt < 2; ++mt)
        #pragma unroll
        for (int nt = 0; nt < 4; ++nt)
          acc[mt][nt] = MFMA16(a1[mt], b1f[ks][nt], acc[mt][nt]);
    }
    #pragma unroll
    for (int mt = 0; mt < 2; ++mt)
      #pragma unroll
      for (int nt = 0; nt < 4; ++nt) {
        int colb = wn * 64 + nt * 16 + l15;
        #pragma unroll
        for (int r = 0; r < 4; ++r) {
          int rowb = wm * 32 + mt * 16 + l4 * 4 + r;
          int gm = row0 + rowb;
          if (gm < M) outB[(size_t)gm * 128 + colb] = f2bf(acc[mt][nt][r] + bb1[nt]);
        }
      }
    row0 = nrow0;
  }
}

// ---------------- persistent pipelined edge block (K=384, gathered ln via LDS) ----------------
__global__ __launch_bounds__(256) void edge_kernel(
    int E, int tiles, int tpb, unsigned short* __restrict__ le,
    const unsigned short* __restrict__ ln,
    const int* __restrict__ row_p, const int* __restrict__ col_p,
    const unsigned short* __restrict__ wt0,  // [128][384]
    const float* __restrict__ b0,
    const unsigned short* __restrict__ wt1, const float* __restrict__ b1) {
  __shared__ __align__(16) unsigned short lnr_lds[64 * 128];
  __shared__ __align__(16) unsigned short lnc_lds[64 * 128];
  __shared__ __align__(16) unsigned short h_lds[64 * 128];
  const int tid = threadIdx.x, wave = tid >> 6, lane = tid & 63;
  const int wm = wave >> 1, wn = wave & 1, l15 = lane & 15, l4 = lane >> 4;
  int t0 = blockIdx.x * tpb, t1 = t0 + tpb; if (t1 > tiles) t1 = tiles;
  if (t0 >= tiles) return;

  // persistent weights: W0 row/col/edge slices + W1 (all L2-hot)
  bf16x8 bR[4][4], bC[4][4], bE[4][4], b1f[4][4];
  float bb0[4], bb1[4];
  #pragma unroll
  for (int nt = 0; nt < 4; ++nt) {
    int n = wn * 64 + nt * 16 + l15;
    bb0[nt] = b0[n]; bb1[nt] = b1[n];
    #pragma unroll
    for (int ks = 0; ks < 4; ++ks) {
      int k = ks * 32 + l4 * 8;
      bR[ks][nt]  = *(const bf16x8*)(wt0 + (size_t)n * 384 + k);
      bC[ks][nt]  = *(const bf16x8*)(wt0 + (size_t)n * 384 + 128 + k);
      bE[ks][nt]  = *(const bf16x8*)(wt0 + (size_t)n * 384 + 256 + k);
      b1f[ks][nt] = *(const bf16x8*)(wt1 + (size_t)n * 128 + k);
    }
  }

  // prologue: prefetch tile t0 (idx -> gathers -> le frags)
  int row0 = t0 * 64;
  int il = row0 + 16 * wave + l15; if (il > E - 1) il = E - 1;
  int myrow = row_p[il], mycol = col_p[il];
  bf16x8 gR[4], gC[4], a[2][4];
  #pragma unroll
  for (int i = 0; i < 4; ++i) {
    int rl = 4 * i + l4;
    int rr = __shfl(myrow, rl, 64);
    int cc = __shfl(mycol, rl, 64);
    gR[i] = *(const bf16x8*)(ln + (size_t)rr * 128 + l15 * 8);
    gC[i] = *(const bf16x8*)(ln + (size_t)cc * 128 + l15 * 8);
  }
  #pragma unroll
  for (int mt = 0; mt < 2; ++mt) {
    int gm = row0 + wm * 32 + mt * 16 + l15; if (gm > E - 1) gm = E - 1;
    #pragma unroll
    for (int ks = 0; ks < 4; ++ks)
      a[mt][ks] = *(const bf16x8*)(le + (size_t)gm * 128 + ks * 32 + l4 * 8);
  }

  for (int t = t0; t < t1; ++t) {
    int tn = (t + 1 < t1) ? (t + 1) : t;
    int nrow0 = tn * 64;
    // [0] idx prefetch for t+1 (L2-resident, arrives before [5])
    int nil = nrow0 + 16 * wave + l15; if (nil > E - 1) nil = E - 1;
    int nmyrow = row_p[nil], nmycol = col_p[nil];
    // [1] ds_write staged gathers (XOR-swizzled chunk)
    #pragma unroll
    for (int i = 0; i < 4; ++i) {
      int rowl = 16 * wave + 4 * i + l4;
      int off = rowl * 128 + ((l15 ^ (rowl & 7)) << 3);
      *(bf16x8*)&lnr_lds[off] = gR[i];
      *(bf16x8*)&lnc_lds[off] = gC[i];
    }
    // [2] layer0, le slice (register A, overlaps ds_write latency)
    f32x4 acc[2][4] = {};
    #pragma unroll
    for (int ks = 0; ks < 4; ++ks)
      #pragma unroll
      for (int mt = 0; mt < 2; ++mt)
        #pragma unroll
        for (int nt = 0; nt < 4; ++nt)
          acc[mt][nt] = MFMA16(a[mt][ks], bE[ks][nt], acc[mt][nt]);
    // [3] barrier A: lnr/lnc visible
    BARRIER_LGKM();
    // [4] layer0, row/col slices from LDS
    #pragma unroll
    for (int ks = 0; ks < 4; ++ks) {
      bf16x8 ar[2], ac[2];
      #pragma unroll
      for (int mt = 0; mt < 2; ++mt) {
        int rowb = wm * 32 + mt * 16 + l15;
        int off = rowb * 128 + (((ks * 4 + l4) ^ (rowb & 7)) << 3);
        ar[mt] = *(const bf16x8*)&lnr_lds[off];
        ac[mt] = *(const bf16x8*)&lnc_lds[off];
      }
      #pragma unroll
      for (int mt = 0; mt < 2; ++mt)
        #pragma unroll
        for (int nt = 0; nt < 4; ++nt) {
          acc[mt][nt] = MFMA16(ar[mt], bR[ks][nt], acc[mt][nt]);
          acc[mt][nt] = MFMA16(ac[mt], bC[ks][nt], acc[mt][nt]);
        }
    }
    // [5] issue t+1 prefetch: gathers + le frags (hidden under [6]-[9] + next [1]-[2])
    #pragma unroll
    for (int i = 0; i < 4; ++i) {
      int rl = 4 * i + l4;
      int rr = __shfl(nmyrow, rl, 64);
      int cc = __shfl(nmycol, rl, 64);
      gR[i] = *(const bf16x8*)(ln + (size_t)rr * 128 + l15 * 8);
      gC[i] = *(const bf16x8*)(ln + (size_t)cc * 128 + l15 * 8);
    }
    #pragma unroll
    for (int mt = 0; mt < 2; ++mt) {
      int gm = nrow0 + wm * 32 + mt * 16 + l15; if (gm > E - 1) gm = E - 1;
      #pragma unroll
      for (int ks = 0; ks < 4; ++ks)
        a[mt][ks] = *(const bf16x8*)(le + (size_t)gm * 128 + ks * 32 + l4 * 8);
    }
    // [6] h = relu(acc + b0) -> h_lds
    #pragma unroll
    for (int mt = 0; mt < 2; ++mt)
      #pragma unroll
      for (int nt = 0; nt < 4; ++nt) {
        int colb = wn * 64 + nt * 16 + l15;
        #pragma unroll
        for (int r = 0; r < 4; ++r) {
          int rowb = wm * 32 + mt * 16 + l4 * 4 + r;
          h_lds[rowb * 128 + (colb ^ ((rowb & 7) << 3))] =
              f2bf(fmaxf(acc[mt][nt][r] + bb0[nt], 0.0f));
        }
      }
    // [7] barrier B
    BARRIER_LGKM();
    // [8] layer1
    f32x4 acc1[2][4] = {};
    #pragma unroll
    for (int ks = 0; ks < 4; ++ks) {
      bf16x8 a1[2];
      #pragma unroll
      for (int mt = 0; mt < 2; ++mt) {
        int rowb = wm * 32 + mt * 16 + l15;
        a1[mt] = *(const bf16x8*)&h_lds[rowb * 128 + ((ks * 32 + l4 * 8) ^ ((rowb & 7) << 3))];
      }
      #pragma unroll
      for (int mt = 0; mt < 2; ++mt)
        #pragma unroll
        for (int nt = 0; nt < 4; ++nt)
          acc1[mt][nt] = MFMA16(a1[mt], b1f[ks][nt], acc1[mt][nt]);
    }
    // [9] store new le
    #pragma unroll
    for (int mt = 0; mt < 2; ++mt)
      #pragma unroll
      for (int nt = 0; nt < 4; ++nt) {
        int colb = wn * 64 + nt * 16 + l15;
        #pragma unroll
        for (int r = 0; r < 4; ++r) {
          int rowb = wm * 32 + mt * 16 + l4 * 4 + r;
          int gm = row0 + rowb;
          if (gm < E) le[(size_t)gm * 128 + colb] = f2bf(acc1[mt][nt][r] + bb1[nt]);
        }
      }
    row0 = nrow0;
  }
}

// ---------------- node block (one-shot; N is small) ----------------
__global__ __launch_bounds__(256) void node_kernel(
    int M, unsigned short* __restrict__ ln, const unsigned short* __restrict__ aggb,
    const unsigned short* __restrict__ wt0, const float* __restrict__ b0,
    const unsigned short* __restrict__ wt1, const float* __restrict__ b1) {
  __shared__ __align__(16) unsigned short h_lds[64 * 128];
  const int tid = threadIdx.x, wave = tid >> 6, lane = tid & 63;
  const int wm = wave >> 1, wn = wave & 1, l15 = lane & 15, l4 = lane >> 4;
  const int row0 = blockIdx.x * 64;

  bf16x8 a[2][8];
  #pragma unroll
  for (int mt = 0; mt < 2; ++mt) {
    int gm = row0 + wm * 32 + mt * 16 + l15; if (gm > M - 1) gm = M - 1;
    #pragma unroll
    for (int ks = 0; ks < 4; ++ks) {
      a[mt][ks]     = *(const bf16x8*)(ln   + (size_t)gm * 128 + ks * 32 + l4 * 8);
      a[mt][4 + ks] = *(const bf16x8*)(aggb + (size_t)gm * 128 + ks * 32 + l4 * 8);
    }
  }
  bf16x8 b0f[8][4];
  #pragma unroll
  for (int nt = 0; nt < 4; ++nt) {
    int n = wn * 64 + nt * 16 + l15;
    #pragma unroll
    for (int ks = 0; ks < 8; ++ks)
      b0f[ks][nt] = *(const bf16x8*)(wt0 + (size_t)n * 256 + ks * 32 + l4 * 8);
  }
  f32x4 acc[2][4] = {};
  #pragma unroll
  for (int ks = 0; ks < 8; ++ks)
    #pragma unroll
    for (int mt = 0; mt < 2; ++mt)
      #pragma unroll
      for (int nt = 0; nt < 4; ++nt)
        acc[mt][nt] = MFMA16(a[mt][ks], b0f[ks][nt], acc[mt][nt]);

  bf16x8 b1f[4][4];
  #pragma unroll
  for (int nt = 0; nt < 4; ++nt) {
    int n = wn * 64 + nt * 16 + l15;
    #pragma unroll
    for (int ks = 0; ks < 4; ++ks)
      b1f[ks][nt] = *(const bf16x8*)(wt1 + (size_t)n * 128 + ks * 32 + l4 * 8);
  }
  #pragma unroll
  for (int mt = 0; mt < 2; ++mt)
    #pragma unroll
    for (int nt = 0; nt < 4; ++nt) {
      int colb = wn * 64 + nt * 16 + l15;
      float bb = b0[colb];
      #pragma unroll
      for (int r = 0; r < 4; ++r) {
        int rowb = wm * 32 + mt * 16 + l4 * 4 + r;
        h_lds[rowb * 128 + (colb ^ ((rowb & 7) << 3))] = f2bf(fmaxf(acc[mt][nt][r] + bb, 0.0f));
      }
    }
  __syncthreads();
  f32x4 acc1[2][4] = {};
  #pragma unroll
  for (int ks = 0; ks < 4; ++ks) {
    bf16x8 a1[2];
    #pragma unroll
    for (int mt = 0; mt < 2; ++mt) {
      int rowb = wm * 32 + mt * 16 + l15;
      a1[mt] = *(const bf16x8*)&h_lds[rowb * 128 + ((ks * 32 + l4 * 8) ^ ((rowb & 7) << 3))];
    }
    #pragma unroll
    for (int mt = 0; mt < 2; ++mt)
      #pragma unroll
      for (int nt = 0; nt < 4; ++nt)
        acc1[mt][nt] = MFMA16(a1[mt], b1f[ks][nt], acc1[mt][nt]);
  }
  #pragma unroll
  for (int mt = 0; mt < 2; ++mt)
    #pragma unroll
    for (int nt = 0; nt < 4; ++nt) {
      int colb = wn * 64 + nt * 16 + l15;
      float bb = b1[colb];
      #pragma unroll
      for (int r = 0; r < 4; ++r) {
        int rowb = wm * 32 + mt * 16 + l4 * 4 + r;
        int gm = row0 + rowb;
        if (gm < M) ln[(size_t)gm * 128 + colb] = f2bf(acc1[mt][nt][r] + bb);
      }
    }
}

// ---------------- persistent pipelined decoder ----------------
__global__ __launch_bounds__(256) void dec_kernel(
    int E, int tiles, int tpb, const unsigned short* __restrict__ le,
    const int* __restrict__ row_p, const int* __restrict__ col_p,
    const int* __restrict__ eid, const float* __restrict__ ea_p,
    const unsigned short* __restrict__ wt0, const float* __restrict__ b0,
    const float* __restrict__ decW1, const float* __restrict__ decB1,
    float* __restrict__ dout) {
  __shared__ float s_dec[2][2][64];
  const int tid = threadIdx.x, wave = tid >> 6, lane = tid & 63;
  const int wm = wave >> 1, wn = wave & 1, l15 = lane & 15, l4 = lane >> 4;
  int t0 = blockIdx.x * tpb, t1 = t0 + tpb; if (t1 > tiles) t1 = tiles;
  if (t0 >= tiles) return;

  bf16x8 b0f[4][4];
  float w1c[4], b0c[4];
  #pragma unroll
  for (int nt = 0; nt < 4; ++nt) {
    int n = wn * 64 + nt * 16 + l15;
    w1c[nt] = decW1[n]; b0c[nt] = b0[n];
    #pragma unroll
    for (int ks = 0; ks < 4; ++ks)
      b0f[ks][nt] = *(const bf16x8*)(wt0 + (size_t)n * 128 + ks * 32 + l4 * 8);
  }
  float db1 = decB1[0];

  int row0 = t0 * 64;
  bf16x8 a[2][4];
  #pragma unroll
  for (int mt = 0; mt < 2; ++mt) {
    int gm = row0 + wm * 32 + mt * 16 + l15; if (gm > E - 1) gm = E - 1;
    #pragma unroll
    for (int ks = 0; ks < 4; ++ks)
      a[mt][ks] = *(const bf16x8*)(le + (size_t)gm * 128 + ks * 32 + l4 * 8);
  }
  int e0 = row0 + (tid & 63); if (e0 > E - 1) e0 = E - 1;
  int rr = row_p[e0], cc = col_p[e0], ee = eid[e0];
  float eav = ea_p[e0];
  int p = 0;

  for (int t = t0; t < t1; ++t) {
    int tn = (t + 1 < t1) ? (t + 1) : t;
    int nrow0 = tn * 64;
    f32x4 acc[2][4] = {};
    #pragma unroll
    for (int ks = 0; ks < 4; ++ks)
      #pragma unroll
      for (int mt = 0; mt < 2; ++mt)
        #pragma unroll
        for (int nt = 0; nt < 4; ++nt)
          acc[mt][nt] = MFMA16(a[mt][ks], b0f[ks][nt], acc[mt][nt]);
    // prefetch t+1
    #pragma unroll
    for (int mt = 0; mt < 2; ++mt) {
      int gm = nrow0 + wm * 32 + mt * 16 + l15; if (gm > E - 1) gm = E - 1;
      #pragma unroll
      for (int ks = 0; ks < 4; ++ks)
        a[mt][ks] = *(const bf16x8*)(le + (size_t)gm * 128 + ks * 32 + l4 * 8);
    }
    int ne0 = nrow0 + (tid & 63); if (ne0 > E - 1) ne0 = E - 1;
    int nrr = row_p[ne0], ncc = col_p[ne0], nee = eid[ne0];
    float neav = ea_p[ne0];

    float part[2][4] = {};
    #pragma unroll
    for (int mt = 0; mt < 2; ++mt)
      #pragma unroll
      for (int nt = 0; nt < 4; ++nt)
        #pragma unroll
        for (int r = 0; r < 4; ++r)
          part[mt][r] += fmaxf(acc[mt][nt][r] + b0c[nt], 0.0f) * w1c[nt];
    #pragma unroll
    for (int mt = 0; mt < 2; ++mt)
      #pragma unroll
      for (int r = 0; r < 4; ++r) {
        float v = part[mt][r];
        #pragma unroll
        for (int off = 1; off < 16; off <<= 1) v += __shfl_xor(v, off, 64);
        if (l15 == 0) s_dec[p][wn][wm * 32 + mt * 16 + l4 * 4 + r] = v;
      }
    BARRIER_LGKM();
    if (tid < 64) {
      int gm = row0 + tid;
      if (gm < E) {
        float v = s_dec[p][0][tid] + s_dec[p][1][tid] + db1;
        if (rr == cc) v = 0.5f * sqrtf(eav);
        dout[ee] = v;
      }
    }
    rr = nrr; cc = ncc; ee = nee; eav = neav;
    row0 = nrow0; p ^= 1;
  }
}

// ---------------- graph prep ----------------
struct TransDesc { const float* src[16]; unsigned short* dst[16]; int K[16]; };

__global__ void trans_kernel(TransDesc td) {
  int m = blockIdx.y;
  int k = blockIdx.x;
  if (k >= td.K[m]) return;
  int n = threadIdx.x;  // 128
  td.dst[m][(size_t)n * td.K[m] + k] = f2bf(td.src[m][(size_t)k * 128 + n]);
}

__global__ void deg_kernel(const int* __restrict__ row, int E, int* cnt) {
  int i = blockIdx.x * blockDim.x + threadIdx.x;
  if (i < E) atomicAdd(&cnt[row[i]], 1);
}

__global__ void invcnt_kernel(const int* __restrict__ cnt, int N, float* inv) {
  int i = blockIdx.x * blockDim.x + threadIdx.x;
  if (i < N) { int c = cnt[i]; inv[i] = 1.0f / (float)(c > 1 ? c : 1); }
}

__global__ __launch_bounds__(1024) void scan_kernel(const int* __restrict__ cnt, int N,
                                                    int* __restrict__ offs, int* __restrict__ cursor) {
  __shared__ int lds[1024];
  __shared__ int carry;
  if (threadIdx.x == 0) carry = 0;
  __syncthreads();
  for (int base = 0; base < N; base += 1024) {
    int i = base + (int)threadIdx.x;
    int v = (i < N) ? cnt[i] : 0;
    lds[threadIdx.x] = v;
    __syncthreads();
    #pragma unroll
    for (int off = 1; off < 1024; off <<= 1) {
      int t = (threadIdx.x >= (unsigned)off) ? lds[threadIdx.x - off] : 0;
      __syncthreads();
      lds[threadIdx.x] += t;
      __syncthreads();
    }
    int excl = lds[threadIdx.x] - v + carry;
    if (i < N) { offs[i] = excl; cursor[i] = excl; }
    __syncthreads();
    if (threadIdx.x == 1023) carry += lds[1023];
    __syncthreads();
  }
}

__global__ void scatter_kernel(const int* __restrict__ row, int E,
                               int* __restrict__ cursor, int* __restrict__ eid) {
  int i = blockIdx.x * blockDim.x + threadIdx.x;
  if (i < E) {
    int r = row[i];
    int pos = atomicAdd(&cursor[r], 1);
    eid[pos] = i;
  }
}

__global__ void permute_kernel(const int* __restrict__ eid,
                               const int* __restrict__ row, const int* __restrict__ col,
                               const float* __restrict__ ea, int E,
                               int* __restrict__ row_p, int* __restrict__ col_p,
                               float* __restrict__ ea_p) {
  int i = blockIdx.x * blockDim.x + threadIdx.x;
  if (i < E) {
    int e = eid[i];
    row_p[i] = row[e];
    col_p[i] = col[e];
    ea_p[i]  = ea[e];
  }
}

__global__ __launch_bounds__(256) void agg_kernel(const unsigned short* __restrict__ le,
                                                  const int* __restrict__ offs,
                                                  const int* __restrict__ cnt,
                                                  const float* __restrict__ inv,
                                                  unsigned short* __restrict__ aggb, int N) {
  int wave = threadIdx.x >> 6, lane = threadIdx.x & 63;
  int n = blockIdx.x * 4 + wave;
  if (n >= N) return;
  int beg = offs[n], d = cnt[n];
  const unsigned short* base = le + (size_t)beg * 128 + lane * 2;
  float sx0 = 0, sy0 = 0, sx1 = 0, sy1 = 0, sx2 = 0, sy2 = 0, sx3 = 0, sy3 = 0;
  int j = 0;
  for (; j + 3 < d; j += 4) {
    ushort2 v0 = *(const ushort2*)(base + (size_t)j * 128);
    ushort2 v1 = *(const ushort2*)(base + (size_t)(j + 1) * 128);
    ushort2 v2 = *(const ushort2*)(base + (size_t)(j + 2) * 128);
    ushort2 v3 = *(const ushort2*)(base + (size_t)(j + 3) * 128);
    sx0 += bf2f(v0.x); sy0 += bf2f(v0.y);
    sx1 += bf2f(v1.x); sy1 += bf2f(v1.y);
    sx2 += bf2f(v2.x); sy2 += bf2f(v2.y);
    sx3 += bf2f(v3.x); sy3 += bf2f(v3.y);
  }
  for (; j < d; ++j) {
    ushort2 v0 = *(const ushort2*)(base + (size_t)j * 128);
    sx0 += bf2f(v0.x); sy0 += bf2f(v0.y);
  }
  float iv = inv[n];
  ushort2 o;
  o.x = f2bf((sx0 + sx1 + sx2 + sx3) * iv);
  o.y = f2bf((sy0 + sy1 + sy2 + sy3) * iv);
  *(ushort2*)(aggb + (size_t)n * 128 + lane * 2) = o;
}

extern "C" void kernel_launch(void* const* d_in, const int* in_sizes, int n_in,
                              void* d_out, int out_size, void* d_ws, size_t ws_size,
                              hipStream_t stream) {
  const float* x         = (const float*)d_in[0];
  const float* edge_attr = (const float*)d_in[1];
  const int*   eidx      = (const int*)  d_in[2];
  const float* encn_W0 = (const float*)d_in[3];
  const float* encn_b0 = (const float*)d_in[4];
  const float* encn_W1 = (const float*)d_in[5];
  const float* encn_b1 = (const float*)d_in[6];
  const float* ence_W0 = (const float*)d_in[7];
  const float* ence_b0 = (const float*)d_in[8];
  const float* ence_W1 = (const float*)d_in[9];
  const float* ence_b1 = (const float*)d_in[10];
  const float* dec_W0  = (const float*)d_in[11];
  const float* dec_b0  = (const float*)d_in[12];
  const float* dec_W1  = (const float*)d_in[13];
  const float* dec_b1  = (const float*)d_in[14];
  const float* eW0 = (const float*)d_in[15];
  const float* eb0 = (const float*)d_in[16];
  const float* eW1 = (const float*)d_in[17];
  const float* eb1 = (const float*)d_in[18];
  const float* nW0 = (const float*)d_in[19];
  const float* nb0 = (const float*)d_in[20];
  const float* nW1 = (const float*)d_in[21];
  const float* nb1 = (const float*)d_in[22];

  const int N = in_sizes[0];
  const int E = in_sizes[1];
  const int* rowI = eidx;
  const int* colI = eidx + E;

  char* w = (char*)d_ws;
  auto take = [&](size_t bytes) -> char* {
    char* p = w; w += (bytes + 255) & ~(size_t)255; return p;
  };
  unsigned short* ln   = (unsigned short*)take((size_t)N * 128 * 2);
  unsigned short* le   = (unsigned short*)take((size_t)E * 128 * 2);  // CSR order
  unsigned short* aggb = (unsigned short*)take((size_t)N * 128 * 2);
  int*            cnt  = (int*)take((size_t)N * 4);
  float*          inv  = (float*)take((size_t)N * 4);
  int*            offs = (int*)take((size_t)N * 4);
  int*            curs = (int*)take((size_t)N * 4);
  int*            eidArr = (int*)take((size_t)E * 4);
  int*            row_p  = (int*)take((size_t)E * 4);
  int*            col_p  = (int*)take((size_t)E * 4);
  float*          ea_p   = (float*)take((size_t)E * 4);
  unsigned short* wt_encn1 = (unsigned short*)take(128 * 128 * 2);
  unsigned short* wt_ence1 = (unsigned short*)take(128 * 128 * 2);
  unsigned short* wt_dec0  = (unsigned short*)take(128 * 128 * 2);
  unsigned short *wt_e0[3], *wt_e1[3], *wt_n0[3], *wt_n1[3];
  for (int s = 0; s < 3; ++s) wt_e0[s] = (unsigned short*)take(384 * 128 * 2);
  for (int s = 0; s < 3; ++s) wt_e1[s] = (unsigned short*)take(128 * 128 * 2);
  for (int s = 0; s < 3; ++s) wt_n0[s] = (unsigned short*)take(256 * 128 * 2);
  for (int s = 0; s < 3; ++s) wt_n1[s] = (unsigned short*)take(128 * 128 * 2);

  TransDesc td{};
  int mi = 0;
  auto add = [&](const float* s, unsigned short* d, int K) {
    td.src[mi] = s; td.dst[mi] = d; td.K[mi] = K; ++mi;
  };
  add(encn_W1, wt_encn1, 128);
  add(ence_W1, wt_ence1, 128);
  add(dec_W0,  wt_dec0,  128);
  for (int s = 0; s < 3; ++s) add(eW0 + (size_t)s * 384 * 128, wt_e0[s], 384);
  for (int s = 0; s < 3; ++s) add(eW1 + (size_t)s * 128 * 128, wt_e1[s], 128);
  for (int s = 0; s < 3; ++s) add(nW0 + (size_t)s * 256 * 128, wt_n0[s], 256);
  for (int s = 0; s < 3; ++s) add(nW1 + (size_t)s * 128 * 128, wt_n1[s], 128);

  hipMemsetAsync(cnt, 0, (size_t)N * 4, stream);
  trans_kernel<<<dim3(384, mi), 128, 0, stream>>>(td);
  deg_kernel<<<(E + 255) / 256, 256, 0, stream>>>(rowI, E, cnt);
  invcnt_kernel<<<(N + 255) / 256, 256, 0, stream>>>(cnt, N, inv);
  scan_kernel<<<1, 1024, 0, stream>>>(cnt, N, offs, curs);
  scatter_kernel<<<(E + 255) / 256, 256, 0, stream>>>(rowI, E, curs, eidArr);
  permute_kernel<<<(E + 255) / 256, 256, 0, stream>>>(eidArr, rowI, colI, edge_attr, E,
                                                      row_p, col_p, ea_p);

  const int tilesN = (N + 63) / 64;
  const int tilesE = (E + 63) / 64;
  const int TPB_ENC = 4, TPB_EDGE = 7, TPB_DEC = 4;
  const int G_ENC_E = (tilesE + TPB_ENC - 1) / TPB_ENC;
  const int G_EDGE  = (tilesE + TPB_EDGE - 1) / TPB_EDGE;
  const int G_DEC   = (tilesE + TPB_DEC - 1) / TPB_DEC;

  enc_kernel<<<tilesN, 256, 0, stream>>>(N, tilesN, 1, x, encn_W0, encn_b0,
                                         wt_encn1, encn_b1, ln);
  enc_kernel<<<G_ENC_E, 256, 0, stream>>>(E, tilesE, TPB_ENC, ea_p, ence_W0, ence_b0,
                                          wt_ence1, ence_b1, le);

  for (int s = 0; s < 3; ++s) {
    edge_kernel<<<G_EDGE, 256, 0, stream>>>(E, tilesE, TPB_EDGE, le, ln, row_p, col_p,
                                            wt_e0[s], eb0 + s * 128,
                                            wt_e1[s], eb1 + s * 128);
    agg_kernel<<<(N + 3) / 4, 256, 0, stream>>>(le, offs, cnt, inv, aggb, N);
    node_kernel<<<(N + 63) / 64, 256, 0, stream>>>(N, ln, aggb, wt_n0[s], nb0 + s * 128,
                                                   wt_n1[s], nb1 + s * 128);
  }
  dec_kernel<<<G_DEC, 256, 0, stream>>>(E, tilesE, TPB_DEC, le, row_p, col_p, eidArr, ea_p,
                                        wt_dec0, dec_b0, dec_W1, dec_b1,
                                        (float*)d_out);
}